// Round 2
// baseline (4500.008 us; speedup 1.0000x reference)
//
#include <hip/hip_runtime.h>
#include <hip/hip_cooperative_groups.h>

namespace cg = cooperative_groups;

typedef unsigned short u16;
typedef short short8 __attribute__((ext_vector_type(8)));
typedef float f32x4 __attribute__((ext_vector_type(4)));

#define LOG2PI_HALF 0.91893853320467274f

// ---- workspace layout (bytes) ----
static constexpr size_t OFF_STATS = 0;                                  // [128][2][64] f32
static constexpr size_t OFF_NEW   = 65536;                              // [128][2048][64] bf16
static constexpr size_t OFF_AT    = OFF_NEW + (size_t)128*2048*64*2;    // [64][4096] bf16 (A^T)
static constexpr size_t OFF_MUW   = OFF_AT   + (size_t)64*4096*2;
static constexpr size_t OFF_SIGW  = OFF_MUW  + (size_t)256*64*2;
static constexpr size_t OFF_ALW   = OFF_SIGW + (size_t)256*64*2;
static constexpr size_t OFF_MUW2  = OFF_ALW  + (size_t)32*64*2;
static constexpr size_t OFF_SIGW2 = OFF_MUW2 + (size_t)256*256*2;
static constexpr size_t OFF_ALW2  = OFF_SIGW2+ (size_t)256*256*2;
static constexpr size_t WS_NEED   = OFF_ALW2 + (size_t)32*32*2;

static __device__ __forceinline__ u16 f2bf(float x) {
  unsigned u = __builtin_bit_cast(unsigned, x);
  u += 0x7fffu + ((u >> 16) & 1u);          // RNE
  return (u16)(u >> 16);
}
static __device__ __forceinline__ float bf2f(u16 b) {
  unsigned u = ((unsigned)b) << 16;
  return __builtin_bit_cast(float, u);
}

// ================= init: convert A^T + weights to bf16, seed step 0 =================
__global__ void init_kernel(
    const float* __restrict__ A, const float* __restrict__ init_w,
    const float* __restrict__ muW, const float* __restrict__ sigW, const float* __restrict__ alW,
    const float* __restrict__ muW2, const float* __restrict__ sigW2, const float* __restrict__ alW2,
    u16* __restrict__ At, u16* __restrict__ new0, float* __restrict__ stats0,
    u16* __restrict__ muWb, u16* __restrict__ sigWb, u16* __restrict__ alWb,
    u16* __restrict__ muW2b, u16* __restrict__ sigW2b, u16* __restrict__ alW2b)
{
  const int total = 560192;
  for (int idx = blockIdx.x*256 + threadIdx.x; idx < total; idx += gridDim.x*256) {
    if (idx < 262144) {                       // At[j][k] = A[k][j], Aflat[k][j]=A[i,d,j], k=i*64+d
      int j = idx >> 12, k = idx & 4095;
      At[idx] = f2bf(A[k*64 + j]);
    } else if (idx < 393216) {                // new_all[0][n][i] = bf16(init_w[i])
      int e = idx - 262144;
      new0[e] = f2bf(init_w[e & 63]);
    } else if (idx < 409600) { int e = idx - 393216; muWb[e]   = f2bf(muW[e]);
    } else if (idx < 425984) { int e = idx - 409600; sigWb[e]  = f2bf(sigW[e]);
    } else if (idx < 428032) { int e = idx - 425984; alWb[e]   = f2bf(alW[e]);
    } else if (idx < 493568) { int e = idx - 428032; muW2b[e]  = f2bf(muW2[e]);
    } else if (idx < 559104) { int e = idx - 493568; sigW2b[e] = f2bf(sigW2[e]);
    } else if (idx < 560128) { int e = idx - 559104; alW2b[e]  = f2bf(alW2[e]);
    } else {                                  // stats[0]: match stored bf16 values exactly -> var==0
      int e = idx - 560128;
      float wv = bf2f(f2bf(init_w[e]));
      stats0[e]      = 2048.0f * wv;
      stats0[64 + e] = 2048.0f * (wv * wv);
    }
  }
}

// ============ persistent chain: all 127 steps, grid.sync between; 128 blk x 512 thr ============
// block owns 16 rows; new kept in LDS f32 across steps; waves split K 8-way (512 each).
__global__ __launch_bounds__(512) void chain_kernel(
    u16* __restrict__ newa, float* stats,
    const float* __restrict__ X,
    const float* __restrict__ enc_w, const float* __restrict__ enc_b,
    const float* __restrict__ bn_g, const float* __restrict__ bn_b,
    const u16* __restrict__ At, const float* __restrict__ init_w)
{
  __shared__ float newf[16][64];
  __shared__ __align__(16) float tmp_s[16][66];
  __shared__ __align__(16) float enc_s[16][68];
  __shared__ float xp_s[16][8];
  __shared__ float ab_s[2][64];
  __shared__ float red_s[8][16][64];
  __shared__ float sred[2][8][64];

  const int tid = threadIdx.x;
  const int n0  = blockIdx.x * 16;
  const int lane = tid & 63, w = tid >> 6;
  const int m = lane & 15, q = lane >> 4;
  cg::grid_group grid = cg::this_grid();

  // seed new_0 = bf16-rounded init_w (matches init_kernel's new0/stats0 exactly)
  for (int e = tid; e < 1024; e += 512) {
    int r = e >> 6, c = e & 63;
    newf[r][c] = bf2f(f2bf(init_w[c]));
  }

  for (int t = 1; t < 128; ++t) {
    if (tid < 64) {
      volatile const float* st = stats + (t-1)*128;
      float mean = st[tid] * (1.0f/2048.0f);
      float var  = st[64+tid] * (1.0f/2048.0f) - mean*mean;
      float a = bn_g[tid] * rsqrtf(var + 1e-5f);
      ab_s[0][tid] = a;
      ab_s[1][tid] = fmaf(-a, mean, bn_b[tid]);
    }
    if (tid < 128) {
      int r = tid >> 3, k = tid & 7;
      xp_s[r][k] = X[(size_t)(n0+r)*1024 + k*128 + (t-1)];
    }
    __syncthreads();

    // tmp = a*new + b  (BN-apply folded), new from LDS f32
    #pragma unroll
    for (int e0 = 0; e0 < 1024; e0 += 512) {
      int e = e0 + tid;
      int mr = e >> 6, i = e & 63;
      tmp_s[mr][i] = fmaf(ab_s[0][i], newf[mr][i], ab_s[1][i]);
    }
    // enc = softsign(xp @ enc_w.T + enc_b)
    {
      int r = tid >> 5, d0 = (tid & 31) * 2;
      #pragma unroll
      for (int dd = 0; dd < 2; ++dd) {
        int d = d0 + dd;
        float a = enc_b[d];
        #pragma unroll
        for (int k = 0; k < 8; ++k) a = fmaf(xp_s[r][k], enc_w[d*8+k], a);
        enc_s[r][d] = a / (1.0f + fabsf(a));
      }
    }
    __syncthreads();

    f32x4 acc[4];
    #pragma unroll
    for (int nt = 0; nt < 4; ++nt) acc[nt] = 0;

    #pragma unroll 4
    for (int it = 0; it < 16; ++it) {
      const int k0 = w*512 + it*32;
      const int i = k0 >> 6;
      const int dbase = (k0 & 63) + q*8;
      const float tv = tmp_s[m][i];
      const f32x4 e0 = *reinterpret_cast<const f32x4*>(&enc_s[m][dbase]);
      const f32x4 e1 = *reinterpret_cast<const f32x4*>(&enc_s[m][dbase+4]);
      short8 af;
      af[0] = (short)f2bf(tv*e0[0]); af[1] = (short)f2bf(tv*e0[1]);
      af[2] = (short)f2bf(tv*e0[2]); af[3] = (short)f2bf(tv*e0[3]);
      af[4] = (short)f2bf(tv*e1[0]); af[5] = (short)f2bf(tv*e1[1]);
      af[6] = (short)f2bf(tv*e1[2]); af[7] = (short)f2bf(tv*e1[3]);
      const u16* bp = At + k0 + q*8;
      #pragma unroll
      for (int nt = 0; nt < 4; ++nt) {
        short8 bfv = *reinterpret_cast<const short8*>(bp + (nt*16 + m)*4096);
        acc[nt] = __builtin_amdgcn_mfma_f32_16x16x32_bf16(af, bfv, acc[nt], 0, 0, 0);
      }
    }
    #pragma unroll
    for (int nt = 0; nt < 4; ++nt)
      #pragma unroll
      for (int rg = 0; rg < 4; ++rg)
        red_s[w][q*4+rg][nt*16+m] = acc[nt][rg];   // D: row=q*4+reg, col=lane&15 (+nt*16)
    __syncthreads();

    {
      u16* no = newa + (size_t)t*2048*64;
      const int c = tid & 63, r0 = tid >> 6;
      float s1 = 0.0f, s2 = 0.0f;
      #pragma unroll
      for (int rr = r0; rr < 16; rr += 8) {
        float v = red_s[0][rr][c] + red_s[1][rr][c] + red_s[2][rr][c] + red_s[3][rr][c]
                + red_s[4][rr][c] + red_s[5][rr][c] + red_s[6][rr][c] + red_s[7][rr][c];
        newf[rr][c] = v;
        no[(n0+rr)*64 + c] = f2bf(v);
        s1 += v; s2 = fmaf(v, v, s2);
      }
      sred[0][r0][c] = s1;
      sred[1][r0][c] = s2;
    }
    __syncthreads();
    if (tid < 64) {
      float S1 = 0.0f, S2 = 0.0f;
      #pragma unroll
      for (int p = 0; p < 8; ++p) { S1 += sred[0][p][tid]; S2 += sred[1][p][tid]; }
      atomicAdd(&stats[t*128 + tid],      S1);
      atomicAdd(&stats[t*128 + 64 + tid], S2);
    }
    grid.sync();
  }
}

// ================= phi: parallel over (t, 32-row tiles); grid 8192 x 256 =================
__global__ __launch_bounds__(256) void phi_kernel(
    const u16* __restrict__ newa, const float* __restrict__ stats,
    const float* __restrict__ X,
    const u16* __restrict__ muWb, const u16* __restrict__ sigWb, const u16* __restrict__ alWb,
    const u16* __restrict__ muW2b, const u16* __restrict__ sigW2b, const u16* __restrict__ alW2b,
    const float* __restrict__ mub, const float* __restrict__ sigb, const float* __restrict__ alb,
    const float* __restrict__ mub2, const float* __restrict__ sigb2, const float* __restrict__ alb2,
    const float* __restrict__ bn_g, const float* __restrict__ bn_b,
    float* __restrict__ outp)
{
  __shared__ __align__(16) u16 h_s[32][72];
  __shared__ __align__(16) u16 smu[32][264];
  __shared__ __align__(16) u16 ssg[32][264];
  __shared__ __align__(16) u16 sal[32][40];
  __shared__ float xc_s[32][8];
  __shared__ float clp_s[32][32];
  __shared__ float alo_s[32][34];
  __shared__ float bias_s[1088];
  __shared__ float ab2[2][64];
  __shared__ float nrm_s[4];

  const int tid = threadIdx.x;
  const int bx = blockIdx.x;
  const int t  = bx & 127;
  const int n0 = (bx >> 7) * 32;
  const int lane = tid & 63, w = tid >> 6;
  const int m = lane & 15, q = lane >> 4;

  const u16*   na = newa + (size_t)t * 2048 * 64;
  const float* st = stats + t * 128;

  for (int e = tid; e < 1088; e += 256) {
    float v;
    if      (e < 256)  v = mub[e];
    else if (e < 512)  v = sigb[e-256];
    else if (e < 544)  v = alb[e-512];
    else if (e < 800)  v = mub2[e-544];
    else if (e < 1056) v = sigb2[e-800];
    else               v = alb2[e-1056];
    bias_s[e] = v;
  }
  if (tid < 64) {
    float mean = st[tid] * (1.0f/2048.0f);
    float var  = st[64+tid] * (1.0f/2048.0f) - mean*mean;
    float a = bn_g[tid] * rsqrtf(var + 1e-5f);
    ab2[0][tid] = a;
    ab2[1][tid] = fmaf(-a, mean, bn_b[tid]);
  }
  __syncthreads();

  // P1: tmp -> softmax h (bf16 LDS), norm partial, xc stage
  {
    const int r = tid >> 3, j8 = tid & 7;
    short8 nv = *reinterpret_cast<const short8*>(na + (n0+r)*64 + j8*8);
    float tv[8];
    float nacc = 0.0f, mx = -3.4e38f;
    #pragma unroll
    for (int j = 0; j < 8; ++j) {
      int i = j8*8 + j;
      float v = fmaf(ab2[0][i], bf2f((u16)nv[j]), ab2[1][i]);
      tv[j] = v;
      nacc = fmaf(v, v, nacc);
      mx = fmaxf(mx, v);
    }
    mx = fmaxf(mx, __shfl_xor(mx, 1));
    mx = fmaxf(mx, __shfl_xor(mx, 2));
    mx = fmaxf(mx, __shfl_xor(mx, 4));
    float se = 0.0f;
    #pragma unroll
    for (int j = 0; j < 8; ++j) { tv[j] = __expf(tv[j] - mx); se += tv[j]; }
    se += __shfl_xor(se, 1);
    se += __shfl_xor(se, 2);
    se += __shfl_xor(se, 4);
    float inv = 1.0f / se;
    #pragma unroll
    for (int j = 0; j < 8; ++j) h_s[r][j8*8+j] = f2bf(tv[j] * inv);
    nacc += __shfl_xor(nacc, 1);
    nacc += __shfl_xor(nacc, 2);
    nacc += __shfl_xor(nacc, 4);
    nacc += __shfl_xor(nacc, 8);
    nacc += __shfl_xor(nacc, 16);
    nacc += __shfl_xor(nacc, 32);
    if (lane == 0) nrm_s[w] = nacc;
    xc_s[r][j8] = X[(size_t)(n0+r)*1024 + j8*128 + t];
  }
  __syncthreads();

  // P2: layer-1 heads: waves 0,1 -> mu cols [0:128),[128:256); waves 2,3 -> sig; wave0 also al
  {
    const u16* W1 = (w < 2) ? muWb : sigWb;
    const int boff = (w < 2) ? 0 : 256;
    const int coloff = (w & 1) * 128;
    f32x4 acc[2][8];
    #pragma unroll
    for (int a_ = 0; a_ < 2; ++a_)
      #pragma unroll
      for (int b_ = 0; b_ < 8; ++b_) acc[a_][b_] = 0;
    #pragma unroll
    for (int mt = 0; mt < 2; ++mt)
      #pragma unroll
      for (int kit = 0; kit < 2; ++kit) {
        short8 af = *reinterpret_cast<const short8*>(&h_s[mt*16+m][kit*32 + q*8]);
        #pragma unroll
        for (int nt = 0; nt < 8; ++nt) {
          int c = coloff + nt*16 + m;
          short8 bfv = *reinterpret_cast<const short8*>(W1 + c*64 + kit*32 + q*8);
          acc[mt][nt] = __builtin_amdgcn_mfma_f32_16x16x32_bf16(af, bfv, acc[mt][nt], 0, 0, 0);
        }
      }
    #pragma unroll
    for (int mt = 0; mt < 2; ++mt)
      #pragma unroll
      for (int nt = 0; nt < 8; ++nt) {
        int col = coloff + nt*16 + m;
        float bia = bias_s[boff + col];
        #pragma unroll
        for (int rg = 0; rg < 4; ++rg) {
          int row = mt*16 + q*4 + rg;
          float v = acc[mt][nt][rg] + bia;
          v = v / (1.0f + fabsf(v));
          ((w < 2) ? smu : ssg)[row][col] = f2bf(v);
        }
      }
  }
  if (w == 0) {  // alpha layer-1
    f32x4 aacc[2][2];
    aacc[0][0] = 0; aacc[0][1] = 0; aacc[1][0] = 0; aacc[1][1] = 0;
    #pragma unroll
    for (int mt = 0; mt < 2; ++mt)
      #pragma unroll
      for (int kit = 0; kit < 2; ++kit) {
        short8 af = *reinterpret_cast<const short8*>(&h_s[mt*16+m][kit*32 + q*8]);
        #pragma unroll
        for (int nt = 0; nt < 2; ++nt) {
          short8 bfv = *reinterpret_cast<const short8*>(alWb + (nt*16+m)*64 + kit*32 + q*8);
          aacc[mt][nt] = __builtin_amdgcn_mfma_f32_16x16x32_bf16(af, bfv, aacc[mt][nt], 0, 0, 0);
        }
      }
    #pragma unroll
    for (int mt = 0; mt < 2; ++mt)
      #pragma unroll
      for (int nt = 0; nt < 2; ++nt) {
        int col = nt*16 + m;
        float bia = bias_s[512 + col];
        #pragma unroll
        for (int rg = 0; rg < 4; ++rg) {
          int row = mt*16 + q*4 + rg;
          float v = aacc[mt][nt][rg] + bia;
          v = v / (1.0f + fabsf(v));
          sal[row][col] = f2bf(v);
        }
      }
  }
  __syncthreads();

  // P3: layer-2 mu+sig GEMMs (wave w -> cols [64w,64w+64)) fused with GMM comp_lp; wave0: al2
  {
    #pragma unroll 1
    for (int mt = 0; mt < 2; ++mt) {
      f32x4 accm[4], accs[4];
      #pragma unroll
      for (int nt = 0; nt < 4; ++nt) { accm[nt] = 0; accs[nt] = 0; }
      for (int kit = 0; kit < 8; ++kit) {
        short8 am_ = *reinterpret_cast<const short8*>(&smu[mt*16+m][kit*32 + q*8]);
        short8 as_ = *reinterpret_cast<const short8*>(&ssg[mt*16+m][kit*32 + q*8]);
        #pragma unroll
        for (int nt = 0; nt < 4; ++nt) {
          int cb = w*64 + nt*16 + m;
          short8 bm = *reinterpret_cast<const short8*>(muW2b + cb*256 + kit*32 + q*8);
          short8 bs = *reinterpret_cast<const short8*>(sigW2b + cb*256 + kit*32 + q*8);
          accm[nt] = __builtin_amdgcn_mfma_f32_16x16x32_bf16(am_, bm, accm[nt], 0, 0, 0);
          accs[nt] = __builtin_amdgcn_mfma_f32_16x16x32_bf16(as_, bs, accs[nt], 0, 0, 0);
        }
      }
      #pragma unroll
      for (int nt = 0; nt < 4; ++nt) {
        int col = w*64 + nt*16 + m;
        int cmix = col >> 3, x = col & 7;
        float bmu = bias_s[544 + col], bsg = bias_s[800 + col];
        #pragma unroll
        for (int rg = 0; rg < 4; ++rg) {
          int row = mt*16 + q*4 + rg;
          float muv = accm[nt][rg] + bmu;
          float lsv = accs[nt][rg] + bsg;
          float z = (xc_s[row][x] - muv) * __expf(-lsv);
          float tt = fmaf(-0.5f*z, z, -lsv) - LOG2PI_HALF;
          tt += __shfl_xor(tt, 1);     // sum over x (lane bits 0..2)
          tt += __shfl_xor(tt, 2);
          tt += __shfl_xor(tt, 4);
          if (x == 0) clp_s[row][cmix] = tt;
        }
      }
    }
    if (w == 0) {  // alpha layer-2 (K=32 -> single MFMA K-step)
      #pragma unroll
      for (int mt = 0; mt < 2; ++mt) {
        f32x4 aacc[2]; aacc[0] = 0; aacc[1] = 0;
        short8 aa = *reinterpret_cast<const short8*>(&sal[mt*16+m][q*8]);
        #pragma unroll
        for (int nt = 0; nt < 2; ++nt) {
          short8 bb = *reinterpret_cast<const short8*>(alW2b + (nt*16+m)*32 + q*8);
          aacc[nt] = __builtin_amdgcn_mfma_f32_16x16x32_bf16(aa, bb, aacc[nt], 0, 0, 0);
        }
        #pragma unroll
        for (int nt = 0; nt < 2; ++nt) {
          int col = nt*16 + m;
          float bia = bias_s[1056 + col];
          #pragma unroll
          for (int rg = 0; rg < 4; ++rg)
            alo_s[mt*16 + q*4 + rg][col] = aacc[nt][rg] + bia;
        }
      }
    }
  }
  __syncthreads();

  // P5: log_softmax(alpha) + comp_lp -> logsumexp -> res; norm finalize
  {
    const int r = tid >> 3, jj = tid & 7;
    float av[4], am = -3.4e38f;
    #pragma unroll
    for (int u = 0; u < 4; ++u) { av[u] = alo_s[r][jj + u*8]; am = fmaxf(am, av[u]); }
    am = fmaxf(am, __shfl_xor(am, 1));
    am = fmaxf(am, __shfl_xor(am, 2));
    am = fmaxf(am, __shfl_xor(am, 4));
    float se = 0.0f;
    #pragma unroll
    for (int u = 0; u < 4; ++u) se += __expf(av[u] - am);
    se += __shfl_xor(se, 1);
    se += __shfl_xor(se, 2);
    se += __shfl_xor(se, 4);
    float la = am + __logf(se);
    float tt4[4], tm = -3.4e38f;
    #pragma unroll
    for (int u = 0; u < 4; ++u) {
      tt4[u] = av[u] - la + clp_s[r][jj + u*8];
      tm = fmaxf(tm, tt4[u]);
    }
    tm = fmaxf(tm, __shfl_xor(tm, 1));
    tm = fmaxf(tm, __shfl_xor(tm, 2));
    tm = fmaxf(tm, __shfl_xor(tm, 4));
    float ts = 0.0f;
    #pragma unroll
    for (int u = 0; u < 4; ++u) ts += __expf(tt4[u] - tm);
    ts += __shfl_xor(ts, 1);
    ts += __shfl_xor(ts, 2);
    ts += __shfl_xor(ts, 4);
    if (jj == 0) atomicAdd(&outp[n0 + r], tm + __logf(ts));
    if (tid == 0) atomicAdd(&outp[2048], nrm_s[0] + nrm_s[1] + nrm_s[2] + nrm_s[3]);
  }
}

extern "C" void kernel_launch(void* const* d_in, const int* in_sizes, int n_in,
                              void* d_out, int out_size, void* d_ws, size_t ws_size,
                              hipStream_t stream) {
  const float* X      = (const float*)d_in[0];
  const float* enc_w  = (const float*)d_in[1];
  const float* enc_b  = (const float*)d_in[2];
  const float* init_w = (const float*)d_in[3];
  const float* A      = (const float*)d_in[4];
  const float* bn_g   = (const float*)d_in[5];
  const float* bn_b   = (const float*)d_in[6];
  const float* muW    = (const float*)d_in[7];
  const float* mub    = (const float*)d_in[8];
  const float* muW2   = (const float*)d_in[9];
  const float* mub2   = (const float*)d_in[10];
  const float* sigW   = (const float*)d_in[11];
  const float* sigb   = (const float*)d_in[12];
  const float* sigW2  = (const float*)d_in[13];
  const float* sigb2  = (const float*)d_in[14];
  const float* alW    = (const float*)d_in[15];
  const float* alb    = (const float*)d_in[16];
  const float* alW2   = (const float*)d_in[17];
  const float* alb2   = (const float*)d_in[18];

  if (ws_size < WS_NEED) return;

  char* ws = (char*)d_ws;
  float* stats = (float*)(ws + OFF_STATS);
  u16* newa    = (u16*)(ws + OFF_NEW);
  u16* At      = (u16*)(ws + OFF_AT);
  u16* muWb    = (u16*)(ws + OFF_MUW);
  u16* sigWb   = (u16*)(ws + OFF_SIGW);
  u16* alWb    = (u16*)(ws + OFF_ALW);
  u16* muW2b   = (u16*)(ws + OFF_MUW2);
  u16* sigW2b  = (u16*)(ws + OFF_SIGW2);
  u16* alW2b   = (u16*)(ws + OFF_ALW2);

  (void)hipMemsetAsync(d_out, 0, (size_t)out_size * sizeof(float), stream);
  (void)hipMemsetAsync(stats, 0, (size_t)128 * 128 * sizeof(float), stream);

  init_kernel<<<dim3(1024), dim3(256), 0, stream>>>(
      A, init_w, muW, sigW, alW, muW2, sigW2, alW2,
      At, newa, stats, muWb, sigWb, alWb, muW2b, sigW2b, alW2b);

  {
    u16* newa_a = newa; float* stats_a = stats;
    const float *X_a = X, *encw_a = enc_w, *encb_a = enc_b, *bng_a = bn_g, *bnb_a = bn_b, *initw_a = init_w;
    const u16* At_a = At;
    void* args[] = { (void*)&newa_a, (void*)&stats_a, (void*)&X_a, (void*)&encw_a, (void*)&encb_a,
                     (void*)&bng_a, (void*)&bnb_a, (void*)&At_a, (void*)&initw_a };
    (void)hipLaunchCooperativeKernel((void*)chain_kernel, dim3(128), dim3(512), args, 0, stream);
  }

  phi_kernel<<<dim3(8192), dim3(256), 0, stream>>>(
      newa, stats, X,
      muWb, sigWb, alWb, muW2b, sigW2b, alW2b,
      mub, sigb, alb, mub2, sigb2, alb2,
      bn_g, bn_b, (float*)d_out);
}

// Round 4
// 3571.107 us; speedup vs baseline: 1.2601x; 1.2601x over previous
//
#include <hip/hip_runtime.h>

typedef unsigned short u16;
typedef short short8 __attribute__((ext_vector_type(8)));
typedef float f32x4 __attribute__((ext_vector_type(4)));
typedef unsigned uint4v __attribute__((ext_vector_type(4)));

#define LOG2PI_HALF 0.91893853320467274f

// ---- workspace layout (bytes) ----
static constexpr size_t OFF_STATS = 0;                                  // [128][2][64] f32
static constexpr size_t OFF_NEW   = 65536;                              // [128][2048][64] bf16
static constexpr size_t OFF_AT    = OFF_NEW + (size_t)128*2048*64*2;    // [64][4096] bf16 (A^T)
static constexpr size_t OFF_MUW   = OFF_AT   + (size_t)64*4096*2;
static constexpr size_t OFF_SIGW  = OFF_MUW  + (size_t)256*64*2;
static constexpr size_t OFF_ALW   = OFF_SIGW + (size_t)256*64*2;
static constexpr size_t OFF_MUW2  = OFF_ALW  + (size_t)32*64*2;
static constexpr size_t OFF_SIGW2 = OFF_MUW2 + (size_t)256*256*2;
static constexpr size_t OFF_ALW2  = OFF_SIGW2+ (size_t)256*256*2;
static constexpr size_t OFF_CNT   = OFF_ALW2 + (size_t)32*32*2;         // [128] int flags
static constexpr size_t WS_NEED   = OFF_CNT + 512;

static __device__ __forceinline__ u16 f2bf(float x) {
  unsigned u = __builtin_bit_cast(unsigned, x);
  u += 0x7fffu + ((u >> 16) & 1u);          // RNE
  return (u16)(u >> 16);
}
static __device__ __forceinline__ float bf2f(u16 b) {
  unsigned u = ((unsigned)b) << 16;
  return __builtin_bit_cast(float, u);
}
static __device__ __forceinline__ unsigned pk2(float a, float b) {
  return ((unsigned)f2bf(b) << 16) | (unsigned)f2bf(a);
}

// ================= init: convert A^T + weights to bf16, seed step 0 =================
__global__ void init_kernel(
    const float* __restrict__ A, const float* __restrict__ init_w,
    const float* __restrict__ muW, const float* __restrict__ sigW, const float* __restrict__ alW,
    const float* __restrict__ muW2, const float* __restrict__ sigW2, const float* __restrict__ alW2,
    u16* __restrict__ At, u16* __restrict__ new0, float* __restrict__ stats0,
    u16* __restrict__ muWb, u16* __restrict__ sigWb, u16* __restrict__ alWb,
    u16* __restrict__ muW2b, u16* __restrict__ sigW2b, u16* __restrict__ alW2b)
{
  const int total = 560192;
  for (int idx = blockIdx.x*256 + threadIdx.x; idx < total; idx += gridDim.x*256) {
    if (idx < 262144) {                       // At[j][k] = A[k][j], Aflat[k][j]=A[i,d,j], k=i*64+d
      int j = idx >> 12, k = idx & 4095;
      At[idx] = f2bf(A[k*64 + j]);
    } else if (idx < 393216) {                // new_all[0][n][i] = bf16(init_w[i])
      int e = idx - 262144;
      new0[e] = f2bf(init_w[e & 63]);
    } else if (idx < 409600) { int e = idx - 393216; muWb[e]   = f2bf(muW[e]);
    } else if (idx < 425984) { int e = idx - 409600; sigWb[e]  = f2bf(sigW[e]);
    } else if (idx < 428032) { int e = idx - 425984; alWb[e]   = f2bf(alW[e]);
    } else if (idx < 493568) { int e = idx - 428032; muW2b[e]  = f2bf(muW2[e]);
    } else if (idx < 559104) { int e = idx - 493568; sigW2b[e] = f2bf(sigW2[e]);
    } else if (idx < 560128) { int e = idx - 559104; alW2b[e]  = f2bf(alW2[e]);
    } else {                                  // stats[0]: match stored bf16 values exactly -> var==0
      int e = idx - 560128;
      float wv = bf2f(f2bf(init_w[e]));
      stats0[e]      = 2048.0f * wv;
      stats0[64 + e] = 2048.0f * (wv * wv);
    }
  }
}

// ============ persistent chain: all 127 steps; hand-rolled stats barrier ============
// 128 blk x 512 thr; block owns 16 rows; new kept in LDS f32; waves split K 8-way.
__global__ __launch_bounds__(512) void chain_kernel(
    u16* __restrict__ newa, float* stats, int* cnt,
    const float* __restrict__ X,
    const float* __restrict__ enc_w, const float* __restrict__ enc_b,
    const float* __restrict__ bn_g, const float* __restrict__ bn_b,
    const u16* __restrict__ At, const float* __restrict__ init_w)
{
  __shared__ float newf[16][64];
  __shared__ __align__(16) float tmp_s[16][66];
  __shared__ __align__(16) float enc_s[16][68];
  __shared__ float xp_s[16][8];
  __shared__ float red_s[8][16][64];
  __shared__ float sred[2][8][64];

  const int tid = threadIdx.x;
  const int n0  = blockIdx.x * 16;
  const int lane = tid & 63, w = tid >> 6;
  const int m = lane & 15, q = lane >> 4;

  // seed new_0 = bf16-rounded init_w (matches init_kernel's new0/stats0 exactly)
  for (int e = tid; e < 1024; e += 512) {
    int r = e >> 6, c = e & 63;
    newf[r][c] = bf2f(f2bf(init_w[c]));
  }

  for (int t = 1; t < 128; ++t) {
    if (tid < 128) {
      int r = tid >> 3, k = tid & 7;
      xp_s[r][k] = X[(size_t)(n0+r)*1024 + k*128 + (t-1)];
    }
    __syncthreads();                                  // (a) xp visible
    // enc = softsign(xp @ enc_w.T + enc_b)  -- independent of stats, overlaps the wait
    {
      int r = tid >> 5, d0 = (tid & 31) * 2;
      #pragma unroll
      for (int dd = 0; dd < 2; ++dd) {
        int d = d0 + dd;
        float a = enc_b[d];
        #pragma unroll
        for (int k = 0; k < 8; ++k) a = fmaf(xp_s[r][k], enc_w[d*8+k], a);
        enc_s[r][d] = a / (1.0f + fabsf(a));
      }
    }
    // wait for previous step's stats (device-scope acquire)
    if (tid == 0 && t >= 2) {
      while (__hip_atomic_load(cnt + (t-1), __ATOMIC_ACQUIRE, __HIP_MEMORY_SCOPE_AGENT) < 128)
        __builtin_amdgcn_s_sleep(2);
    }
    __syncthreads();                                  // (b) enc visible + stats ready

    // tmp = a*new + b  (BN coeffs computed inline per element)
    #pragma unroll
    for (int e0 = 0; e0 < 1024; e0 += 512) {
      int e = e0 + tid;
      int mr = e >> 6, i = e & 63;
      float a, b;
      if (t == 1) {
        float mean = bf2f(f2bf(init_w[i]));
        a = bn_g[i] * rsqrtf(1e-5f);
        b = fmaf(-a, mean, bn_b[i]);
      } else {
        float s1 = __hip_atomic_load(stats + (t-1)*128 + i,      __ATOMIC_RELAXED, __HIP_MEMORY_SCOPE_AGENT);
        float s2 = __hip_atomic_load(stats + (t-1)*128 + 64 + i, __ATOMIC_RELAXED, __HIP_MEMORY_SCOPE_AGENT);
        float mean = s1 * (1.0f/2048.0f);
        float var  = s2 * (1.0f/2048.0f) - mean*mean;
        a = bn_g[i] * rsqrtf(var + 1e-5f);
        b = fmaf(-a, mean, bn_b[i]);
      }
      tmp_s[mr][i] = fmaf(a, newf[mr][i], b);
    }
    __syncthreads();                                  // (c) tmp visible

    f32x4 acc[4];
    #pragma unroll
    for (int nt = 0; nt < 4; ++nt) acc[nt] = 0;

    #pragma unroll 4
    for (int it = 0; it < 16; ++it) {
      const int k0 = w*512 + it*32;
      const int i = k0 >> 6;
      const int dbase = (k0 & 63) + q*8;
      const float tv = tmp_s[m][i];
      const f32x4 e0 = *reinterpret_cast<const f32x4*>(&enc_s[m][dbase]);
      const f32x4 e1 = *reinterpret_cast<const f32x4*>(&enc_s[m][dbase+4]);
      uint4v pk;
      pk[0] = pk2(tv*e0[0], tv*e0[1]);
      pk[1] = pk2(tv*e0[2], tv*e0[3]);
      pk[2] = pk2(tv*e1[0], tv*e1[1]);
      pk[3] = pk2(tv*e1[2], tv*e1[3]);
      short8 af = __builtin_bit_cast(short8, pk);
      const u16* bp = At + k0 + q*8;
      #pragma unroll
      for (int nt = 0; nt < 4; ++nt) {
        short8 bfv = *reinterpret_cast<const short8*>(bp + (nt*16 + m)*4096);
        acc[nt] = __builtin_amdgcn_mfma_f32_16x16x32_bf16(af, bfv, acc[nt], 0, 0, 0);
      }
    }
    #pragma unroll
    for (int nt = 0; nt < 4; ++nt)
      #pragma unroll
      for (int rg = 0; rg < 4; ++rg)
        red_s[w][q*4+rg][nt*16+m] = acc[nt][rg];   // D: row=q*4+reg, col=lane&15 (+nt*16)
    __syncthreads();                                  // (d)

    {
      u16* no = newa + (size_t)t*2048*64;
      const int c = tid & 63, r0 = tid >> 6;
      float s1 = 0.0f, s2 = 0.0f;
      #pragma unroll
      for (int rr = r0; rr < 16; rr += 8) {
        float v = red_s[0][rr][c] + red_s[1][rr][c] + red_s[2][rr][c] + red_s[3][rr][c]
                + red_s[4][rr][c] + red_s[5][rr][c] + red_s[6][rr][c] + red_s[7][rr][c];
        newf[rr][c] = v;
        no[(n0+rr)*64 + c] = f2bf(v);
        s1 += v; s2 = fmaf(v, v, s2);
      }
      sred[0][r0][c] = s1;
      sred[1][r0][c] = s2;
    }
    __syncthreads();                                  // (e)
    if (tid < 64) {
      float S1 = 0.0f, S2 = 0.0f;
      #pragma unroll
      for (int p = 0; p < 8; ++p) { S1 += sred[0][p][tid]; S2 += sred[1][p][tid]; }
      atomicAdd(&stats[t*128 + tid],      S1);
      atomicAdd(&stats[t*128 + 64 + tid], S2);
    }
    __syncthreads();                                  // (f) stats adds drained
    if (tid == 0)
      __hip_atomic_fetch_add(cnt + t, 1, __ATOMIC_RELEASE, __HIP_MEMORY_SCOPE_AGENT);
  }
}

// ================= phi: parallel over (t, 32-row tiles); grid 8192 x 256 =================
__global__ __launch_bounds__(256) void phi_kernel(
    const u16* __restrict__ newa, const float* __restrict__ stats,
    const float* __restrict__ X,
    const u16* __restrict__ muWb, const u16* __restrict__ sigWb, const u16* __restrict__ alWb,
    const u16* __restrict__ muW2b, const u16* __restrict__ sigW2b, const u16* __restrict__ alW2b,
    const float* __restrict__ mub, const float* __restrict__ sigb, const float* __restrict__ alb,
    const float* __restrict__ mub2, const float* __restrict__ sigb2, const float* __restrict__ alb2,
    const float* __restrict__ bn_g, const float* __restrict__ bn_b,
    float* __restrict__ outp)
{
  __shared__ __align__(16) u16 h_s[32][72];
  __shared__ __align__(16) u16 smu[32][264];
  __shared__ __align__(16) u16 ssg[32][264];
  __shared__ __align__(16) u16 sal[32][40];
  __shared__ float xc_s[32][8];
  __shared__ float clp_s[32][32];
  __shared__ float alo_s[32][34];
  __shared__ float bias_s[1088];
  __shared__ float ab2[2][64];
  __shared__ float nrm_s[4];

  const int tid = threadIdx.x;
  const int bx = blockIdx.x;
  const int t  = bx & 127;
  const int n0 = (bx >> 7) * 32;
  const int lane = tid & 63, w = tid >> 6;
  const int m = lane & 15, q = lane >> 4;

  const u16*   na = newa + (size_t)t * 2048 * 64;
  const float* st = stats + t * 128;

  for (int e = tid; e < 1088; e += 256) {
    float v;
    if      (e < 256)  v = mub[e];
    else if (e < 512)  v = sigb[e-256];
    else if (e < 544)  v = alb[e-512];
    else if (e < 800)  v = mub2[e-544];
    else if (e < 1056) v = sigb2[e-800];
    else               v = alb2[e-1056];
    bias_s[e] = v;
  }
  if (tid < 64) {
    float mean = st[tid] * (1.0f/2048.0f);
    float var  = st[64+tid] * (1.0f/2048.0f) - mean*mean;
    float a = bn_g[tid] * rsqrtf(var + 1e-5f);
    ab2[0][tid] = a;
    ab2[1][tid] = fmaf(-a, mean, bn_b[tid]);
  }
  __syncthreads();

  // P1: tmp -> softmax h (bf16 LDS), norm partial, xc stage
  {
    const int r = tid >> 3, j8 = tid & 7;
    short8 nv = *reinterpret_cast<const short8*>(na + (n0+r)*64 + j8*8);
    float tv[8];
    float nacc = 0.0f, mx = -3.4e38f;
    #pragma unroll
    for (int j = 0; j < 8; ++j) {
      int i = j8*8 + j;
      float v = fmaf(ab2[0][i], bf2f((u16)nv[j]), ab2[1][i]);
      tv[j] = v;
      nacc = fmaf(v, v, nacc);
      mx = fmaxf(mx, v);
    }
    mx = fmaxf(mx, __shfl_xor(mx, 1));
    mx = fmaxf(mx, __shfl_xor(mx, 2));
    mx = fmaxf(mx, __shfl_xor(mx, 4));
    float se = 0.0f;
    #pragma unroll
    for (int j = 0; j < 8; ++j) { tv[j] = __expf(tv[j] - mx); se += tv[j]; }
    se += __shfl_xor(se, 1);
    se += __shfl_xor(se, 2);
    se += __shfl_xor(se, 4);
    float inv = 1.0f / se;
    #pragma unroll
    for (int j = 0; j < 8; ++j) h_s[r][j8*8+j] = f2bf(tv[j] * inv);
    nacc += __shfl_xor(nacc, 1);
    nacc += __shfl_xor(nacc, 2);
    nacc += __shfl_xor(nacc, 4);
    nacc += __shfl_xor(nacc, 8);
    nacc += __shfl_xor(nacc, 16);
    nacc += __shfl_xor(nacc, 32);
    if (lane == 0) nrm_s[w] = nacc;
    xc_s[r][j8] = X[(size_t)(n0+r)*1024 + j8*128 + t];
  }
  __syncthreads();

  // P2: layer-1 heads: waves 0,1 -> mu cols [0:128),[128:256); waves 2,3 -> sig; wave0 also al
  {
    const u16* W1 = (w < 2) ? muWb : sigWb;
    const int boff = (w < 2) ? 0 : 256;
    const int coloff = (w & 1) * 128;
    f32x4 acc[2][8];
    #pragma unroll
    for (int a_ = 0; a_ < 2; ++a_)
      #pragma unroll
      for (int b_ = 0; b_ < 8; ++b_) acc[a_][b_] = 0;
    #pragma unroll
    for (int mt = 0; mt < 2; ++mt)
      #pragma unroll
      for (int kit = 0; kit < 2; ++kit) {
        short8 af = *reinterpret_cast<const short8*>(&h_s[mt*16+m][kit*32 + q*8]);
        #pragma unroll
        for (int nt = 0; nt < 8; ++nt) {
          int c = coloff + nt*16 + m;
          short8 bfv = *reinterpret_cast<const short8*>(W1 + c*64 + kit*32 + q*8);
          acc[mt][nt] = __builtin_amdgcn_mfma_f32_16x16x32_bf16(af, bfv, acc[mt][nt], 0, 0, 0);
        }
      }
    #pragma unroll
    for (int mt = 0; mt < 2; ++mt)
      #pragma unroll
      for (int nt = 0; nt < 8; ++nt) {
        int col = coloff + nt*16 + m;
        float bia = bias_s[boff + col];
        #pragma unroll
        for (int rg = 0; rg < 4; ++rg) {
          int row = mt*16 + q*4 + rg;
          float v = acc[mt][nt][rg] + bia;
          v = v / (1.0f + fabsf(v));
          ((w < 2) ? smu : ssg)[row][col] = f2bf(v);
        }
      }
  }
  if (w == 0) {  // alpha layer-1
    f32x4 aacc[2][2];
    aacc[0][0] = 0; aacc[0][1] = 0; aacc[1][0] = 0; aacc[1][1] = 0;
    #pragma unroll
    for (int mt = 0; mt < 2; ++mt)
      #pragma unroll
      for (int kit = 0; kit < 2; ++kit) {
        short8 af = *reinterpret_cast<const short8*>(&h_s[mt*16+m][kit*32 + q*8]);
        #pragma unroll
        for (int nt = 0; nt < 2; ++nt) {
          short8 bfv = *reinterpret_cast<const short8*>(alWb + (nt*16+m)*64 + kit*32 + q*8);
          aacc[mt][nt] = __builtin_amdgcn_mfma_f32_16x16x32_bf16(af, bfv, aacc[mt][nt], 0, 0, 0);
        }
      }
    #pragma unroll
    for (int mt = 0; mt < 2; ++mt)
      #pragma unroll
      for (int nt = 0; nt < 2; ++nt) {
        int col = nt*16 + m;
        float bia = bias_s[512 + col];
        #pragma unroll
        for (int rg = 0; rg < 4; ++rg) {
          int row = mt*16 + q*4 + rg;
          float v = aacc[mt][nt][rg] + bia;
          v = v / (1.0f + fabsf(v));
          sal[row][col] = f2bf(v);
        }
      }
  }
  __syncthreads();

  // P3: layer-2 mu+sig GEMMs (wave w -> cols [64w,64w+64)) fused with GMM comp_lp; wave0: al2
  {
    #pragma unroll 1
    for (int mt = 0; mt < 2; ++mt) {
      f32x4 accm[4], accs[4];
      #pragma unroll
      for (int nt = 0; nt < 4; ++nt) { accm[nt] = 0; accs[nt] = 0; }
      for (int kit = 0; kit < 8; ++kit) {
        short8 am_ = *reinterpret_cast<const short8*>(&smu[mt*16+m][kit*32 + q*8]);
        short8 as_ = *reinterpret_cast<const short8*>(&ssg[mt*16+m][kit*32 + q*8]);
        #pragma unroll
        for (int nt = 0; nt < 4; ++nt) {
          int cb = w*64 + nt*16 + m;
          short8 bm = *reinterpret_cast<const short8*>(muW2b + cb*256 + kit*32 + q*8);
          short8 bs = *reinterpret_cast<const short8*>(sigW2b + cb*256 + kit*32 + q*8);
          accm[nt] = __builtin_amdgcn_mfma_f32_16x16x32_bf16(am_, bm, accm[nt], 0, 0, 0);
          accs[nt] = __builtin_amdgcn_mfma_f32_16x16x32_bf16(as_, bs, accs[nt], 0, 0, 0);
        }
      }
      #pragma unroll
      for (int nt = 0; nt < 4; ++nt) {
        int col = w*64 + nt*16 + m;
        int cmix = col >> 3, x = col & 7;
        float bmu = bias_s[544 + col], bsg = bias_s[800 + col];
        #pragma unroll
        for (int rg = 0; rg < 4; ++rg) {
          int row = mt*16 + q*4 + rg;
          float muv = accm[nt][rg] + bmu;
          float lsv = accs[nt][rg] + bsg;
          float z = (xc_s[row][x] - muv) * __expf(-lsv);
          float tt = fmaf(-0.5f*z, z, -lsv) - LOG2PI_HALF;
          tt += __shfl_xor(tt, 1);     // sum over x (lane bits 0..2)
          tt += __shfl_xor(tt, 2);
          tt += __shfl_xor(tt, 4);
          if (x == 0) clp_s[row][cmix] = tt;
        }
      }
    }
    if (w == 0) {  // alpha layer-2 (K=32 -> single MFMA K-step)
      #pragma unroll
      for (int mt = 0; mt < 2; ++mt) {
        f32x4 aacc[2]; aacc[0] = 0; aacc[1] = 0;
        short8 aa = *reinterpret_cast<const short8*>(&sal[mt*16+m][q*8]);
        #pragma unroll
        for (int nt = 0; nt < 2; ++nt) {
          short8 bb = *reinterpret_cast<const short8*>(alW2b + (nt*16+m)*32 + q*8);
          aacc[nt] = __builtin_amdgcn_mfma_f32_16x16x32_bf16(aa, bb, aacc[nt], 0, 0, 0);
        }
        #pragma unroll
        for (int nt = 0; nt < 2; ++nt) {
          int col = nt*16 + m;
          float bia = bias_s[1056 + col];
          #pragma unroll
          for (int rg = 0; rg < 4; ++rg)
            alo_s[mt*16 + q*4 + rg][col] = aacc[nt][rg] + bia;
        }
      }
    }
  }
  __syncthreads();

  // P5: log_softmax(alpha) + comp_lp -> logsumexp -> res; norm finalize
  {
    const int r = tid >> 3, jj = tid & 7;
    float av[4], am = -3.4e38f;
    #pragma unroll
    for (int u = 0; u < 4; ++u) { av[u] = alo_s[r][jj + u*8]; am = fmaxf(am, av[u]); }
    am = fmaxf(am, __shfl_xor(am, 1));
    am = fmaxf(am, __shfl_xor(am, 2));
    am = fmaxf(am, __shfl_xor(am, 4));
    float se = 0.0f;
    #pragma unroll
    for (int u = 0; u < 4; ++u) se += __expf(av[u] - am);
    se += __shfl_xor(se, 1);
    se += __shfl_xor(se, 2);
    se += __shfl_xor(se, 4);
    float la = am + __logf(se);
    float tt4[4], tm = -3.4e38f;
    #pragma unroll
    for (int u = 0; u < 4; ++u) {
      tt4[u] = av[u] - la + clp_s[r][jj + u*8];
      tm = fmaxf(tm, tt4[u]);
    }
    tm = fmaxf(tm, __shfl_xor(tm, 1));
    tm = fmaxf(tm, __shfl_xor(tm, 2));
    tm = fmaxf(tm, __shfl_xor(tm, 4));
    float ts = 0.0f;
    #pragma unroll
    for (int u = 0; u < 4; ++u) ts += __expf(tt4[u] - tm);
    ts += __shfl_xor(ts, 1);
    ts += __shfl_xor(ts, 2);
    ts += __shfl_xor(ts, 4);
    if (jj == 0) atomicAdd(&outp[n0 + r], tm + __logf(ts));
    if (tid == 0) atomicAdd(&outp[2048], nrm_s[0] + nrm_s[1] + nrm_s[2] + nrm_s[3]);
  }
}

extern "C" void kernel_launch(void* const* d_in, const int* in_sizes, int n_in,
                              void* d_out, int out_size, void* d_ws, size_t ws_size,
                              hipStream_t stream) {
  const float* X      = (const float*)d_in[0];
  const float* enc_w  = (const float*)d_in[1];
  const float* enc_b  = (const float*)d_in[2];
  const float* init_w = (const float*)d_in[3];
  const float* A      = (const float*)d_in[4];
  const float* bn_g   = (const float*)d_in[5];
  const float* bn_b   = (const float*)d_in[6];
  const float* muW    = (const float*)d_in[7];
  const float* mub    = (const float*)d_in[8];
  const float* muW2   = (const float*)d_in[9];
  const float* mub2   = (const float*)d_in[10];
  const float* sigW   = (const float*)d_in[11];
  const float* sigb   = (const float*)d_in[12];
  const float* sigW2  = (const float*)d_in[13];
  const float* sigb2  = (const float*)d_in[14];
  const float* alW    = (const float*)d_in[15];
  const float* alb    = (const float*)d_in[16];
  const float* alW2   = (const float*)d_in[17];
  const float* alb2   = (const float*)d_in[18];

  if (ws_size < WS_NEED) return;

  char* ws = (char*)d_ws;
  float* stats = (float*)(ws + OFF_STATS);
  u16* newa    = (u16*)(ws + OFF_NEW);
  u16* At      = (u16*)(ws + OFF_AT);
  u16* muWb    = (u16*)(ws + OFF_MUW);
  u16* sigWb   = (u16*)(ws + OFF_SIGW);
  u16* alWb    = (u16*)(ws + OFF_ALW);
  u16* muW2b   = (u16*)(ws + OFF_MUW2);
  u16* sigW2b  = (u16*)(ws + OFF_SIGW2);
  u16* alW2b   = (u16*)(ws + OFF_ALW2);
  int* cnt     = (int*)(ws + OFF_CNT);

  (void)hipMemsetAsync(d_out, 0, (size_t)out_size * sizeof(float), stream);
  (void)hipMemsetAsync(stats, 0, (size_t)128 * 128 * sizeof(float), stream);
  (void)hipMemsetAsync(cnt, 0, 512, stream);

  init_kernel<<<dim3(1024), dim3(256), 0, stream>>>(
      A, init_w, muW, sigW, alW, muW2, sigW2, alW2,
      At, newa, stats, muWb, sigWb, alWb, muW2b, sigW2b, alW2b);

  {
    u16* newa_a = newa; float* stats_a = stats; int* cnt_a = cnt;
    const float *X_a = X, *encw_a = enc_w, *encb_a = enc_b, *bng_a = bn_g, *bnb_a = bn_b, *initw_a = init_w;
    const u16* At_a = At;
    void* args[] = { (void*)&newa_a, (void*)&stats_a, (void*)&cnt_a, (void*)&X_a, (void*)&encw_a,
                     (void*)&encb_a, (void*)&bng_a, (void*)&bnb_a, (void*)&At_a, (void*)&initw_a };
    (void)hipLaunchCooperativeKernel((void*)chain_kernel, dim3(128), dim3(512), args, 0, stream);
  }

  phi_kernel<<<dim3(8192), dim3(256), 0, stream>>>(
      newa, stats, X,
      muWb, sigWb, alWb, muW2b, sigW2b, alW2b,
      mub, sigb, alb, mub2, sigb2, alb2,
      bn_g, bn_b, (float*)d_out);
}

// Round 5
// 3379.494 us; speedup vs baseline: 1.3316x; 1.0567x over previous
//
#include <hip/hip_runtime.h>

typedef unsigned short u16;
typedef short short8 __attribute__((ext_vector_type(8)));
typedef float f32x4 __attribute__((ext_vector_type(4)));
typedef unsigned uint4v __attribute__((ext_vector_type(4)));

#define LOG2PI_HALF 0.91893853320467274f

// ---- workspace layout (bytes) ----
static constexpr size_t OFF_STATS = 0;                                  // [128][2][64] f32
static constexpr size_t OFF_NEW   = 65536;                              // [128][2048][64] bf16
static constexpr size_t OFF_AT    = OFF_NEW + (size_t)128*2048*64*2;    // [64][4096] bf16 (A^T)
static constexpr size_t OFF_MUW   = OFF_AT   + (size_t)64*4096*2;
static constexpr size_t OFF_SIGW  = OFF_MUW  + (size_t)256*64*2;
static constexpr size_t OFF_ALW   = OFF_SIGW + (size_t)256*64*2;
static constexpr size_t OFF_MUW2  = OFF_ALW  + (size_t)32*64*2;
static constexpr size_t OFF_SIGW2 = OFF_MUW2 + (size_t)256*256*2;
static constexpr size_t OFF_ALW2  = OFF_SIGW2+ (size_t)256*256*2;
static constexpr size_t OFF_CNT   = OFF_ALW2 + (size_t)32*32*2;         // [128] int flags
static constexpr size_t OFF_PART  = OFF_CNT + 512;                      // [2][128][128] f32 partial stats
static constexpr size_t WS_NEED   = OFF_PART + (size_t)2*128*128*4;

static __device__ __forceinline__ u16 f2bf(float x) {
  unsigned u = __builtin_bit_cast(unsigned, x);
  u += 0x7fffu + ((u >> 16) & 1u);          // RNE
  return (u16)(u >> 16);
}
static __device__ __forceinline__ float bf2f(u16 b) {
  unsigned u = ((unsigned)b) << 16;
  return __builtin_bit_cast(float, u);
}
static __device__ __forceinline__ unsigned pk2(float a, float b) {
  return ((unsigned)f2bf(b) << 16) | (unsigned)f2bf(a);
}

// ================= init: convert A^T + weights to bf16, seed step 0 =================
__global__ void init_kernel(
    const float* __restrict__ A, const float* __restrict__ init_w,
    const float* __restrict__ muW, const float* __restrict__ sigW, const float* __restrict__ alW,
    const float* __restrict__ muW2, const float* __restrict__ sigW2, const float* __restrict__ alW2,
    u16* __restrict__ At, u16* __restrict__ new0, float* __restrict__ stats0,
    u16* __restrict__ muWb, u16* __restrict__ sigWb, u16* __restrict__ alWb,
    u16* __restrict__ muW2b, u16* __restrict__ sigW2b, u16* __restrict__ alW2b)
{
  const int total = 560192;
  for (int idx = blockIdx.x*256 + threadIdx.x; idx < total; idx += gridDim.x*256) {
    if (idx < 262144) {                       // At[j][k] = A[k][j], Aflat[k][j]=A[i,d,j], k=i*64+d
      int j = idx >> 12, k = idx & 4095;
      At[idx] = f2bf(A[k*64 + j]);
    } else if (idx < 393216) {                // new_all[0][n][i] = bf16(init_w[i])
      int e = idx - 262144;
      new0[e] = f2bf(init_w[e & 63]);
    } else if (idx < 409600) { int e = idx - 393216; muWb[e]   = f2bf(muW[e]);
    } else if (idx < 425984) { int e = idx - 409600; sigWb[e]  = f2bf(sigW[e]);
    } else if (idx < 428032) { int e = idx - 425984; alWb[e]   = f2bf(alW[e]);
    } else if (idx < 493568) { int e = idx - 428032; muW2b[e]  = f2bf(muW2[e]);
    } else if (idx < 559104) { int e = idx - 493568; sigW2b[e] = f2bf(sigW2[e]);
    } else if (idx < 560128) { int e = idx - 559104; alW2b[e]  = f2bf(alW2[e]);
    } else {                                  // stats[0]: match stored bf16 values exactly -> var==0
      int e = idx - 560128;
      float wv = bf2f(f2bf(init_w[e]));
      stats0[e]      = 2048.0f * wv;
      stats0[64 + e] = 2048.0f * (wv * wv);
    }
  }
}

// ============ persistent chain: all 127 steps; partial-stats handoff, relaxed spin ============
// 128 blk x 512 thr; block owns 16 rows; new kept in LDS f32; waves split K 8-way.
__global__ __launch_bounds__(512) void chain_kernel(
    u16* __restrict__ newa, float* stats, int* cnt, float* part,
    const float* __restrict__ X,
    const float* __restrict__ enc_w, const float* __restrict__ enc_b,
    const float* __restrict__ bn_g, const float* __restrict__ bn_b,
    const u16* __restrict__ At, const float* __restrict__ init_w)
{
  __shared__ float newf[16][64];
  __shared__ __align__(16) float tmp_s[16][66];
  __shared__ __align__(16) float enc_s[16][68];
  __shared__ float xp_s[16][8];
  __shared__ float ab_s[2][64];
  __shared__ float psum[4][128];
  __shared__ float red_s[8][16][64];
  __shared__ float sred[2][8][64];

  const int tid = threadIdx.x;
  const int bid = blockIdx.x;
  const int n0  = bid * 16;
  const int lane = tid & 63, w = tid >> 6;
  const int m = lane & 15, q = lane >> 4;

  // seed new_0 = bf16-rounded init_w (matches init_kernel's new0/stats0 exactly)
  for (int e = tid; e < 1024; e += 512) {
    int r = e >> 6, c = e & 63;
    newf[r][c] = bf2f(f2bf(init_w[c]));
  }

  for (int t = 1; t < 128; ++t) {
    if (tid < 128) {
      int r = tid >> 3, k = tid & 7;
      xp_s[r][k] = X[(size_t)(n0+r)*1024 + k*128 + (t-1)];
    }
    __syncthreads();                                  // (a) xp visible
    // enc = softsign(xp @ enc_w.T + enc_b)  -- independent of stats
    {
      int r = tid >> 5, d0 = (tid & 31) * 2;
      #pragma unroll
      for (int dd = 0; dd < 2; ++dd) {
        int d = d0 + dd;
        float a = enc_b[d];
        #pragma unroll
        for (int k = 0; k < 8; ++k) a = fmaf(xp_s[r][k], enc_w[d*8+k], a);
        enc_s[r][d] = a / (1.0f + fabsf(a));
      }
    }

    if (t >= 2) {
      // relaxed spin: NO cache-invalidate per poll (keeps At L2-resident)
      if (tid == 0) {
        while (__hip_atomic_load(cnt + (t-1), __ATOMIC_RELAXED, __HIP_MEMORY_SCOPE_AGENT) < 128)
          __builtin_amdgcn_s_sleep(2);
      }
      __syncthreads();                                // (a2) all proceed past spin
      __atomic_signal_fence(__ATOMIC_ACQUIRE);
      // reduce 128 per-block partials (sc1 loads bypass stale caches)
      {
        const int e = tid & 127, pr = tid >> 7;       // pr in [0,4)
        const float* pb = part + (size_t)((t-1)&1)*16384 + e;
        float s = 0.0f;
        #pragma unroll 8
        for (int p = pr*32; p < pr*32 + 32; ++p)
          s += __hip_atomic_load(pb + p*128, __ATOMIC_RELAXED, __HIP_MEMORY_SCOPE_AGENT);
        psum[pr][e] = s;
      }
      __syncthreads();                                // (b1) psum visible
      if (bid == 0 && tid < 128)                      // publish stats[t-1] for phi
        stats[(t-1)*128 + tid] = psum[0][tid] + psum[1][tid] + psum[2][tid] + psum[3][tid];
      if (tid < 64) {
        float S1 = psum[0][tid] + psum[1][tid] + psum[2][tid] + psum[3][tid];
        float S2 = psum[0][tid+64] + psum[1][tid+64] + psum[2][tid+64] + psum[3][tid+64];
        float mean = S1 * (1.0f/2048.0f);
        float var  = S2 * (1.0f/2048.0f) - mean*mean;
        float a = bn_g[tid] * rsqrtf(var + 1e-5f);
        ab_s[0][tid] = a;
        ab_s[1][tid] = fmaf(-a, mean, bn_b[tid]);
      }
    } else {
      if (tid < 64) {
        float mean = bf2f(f2bf(init_w[tid]));
        float a = bn_g[tid] * rsqrtf(1e-5f);
        ab_s[0][tid] = a;
        ab_s[1][tid] = fmaf(-a, mean, bn_b[tid]);
      }
    }
    __syncthreads();                                  // (b2) ab_s + enc_s visible

    // tmp = a*new + b
    #pragma unroll
    for (int e0 = 0; e0 < 1024; e0 += 512) {
      int e = e0 + tid;
      int mr = e >> 6, i = e & 63;
      tmp_s[mr][i] = fmaf(ab_s[0][i], newf[mr][i], ab_s[1][i]);
    }
    __syncthreads();                                  // (c) tmp visible

    f32x4 acc[4];
    #pragma unroll
    for (int nt = 0; nt < 4; ++nt) acc[nt] = 0;

    #pragma unroll 4
    for (int it = 0; it < 16; ++it) {
      const int k0 = w*512 + it*32;
      const int i = k0 >> 6;
      const int dbase = (k0 & 63) + q*8;
      const float tv = tmp_s[m][i];
      const f32x4 e0 = *reinterpret_cast<const f32x4*>(&enc_s[m][dbase]);
      const f32x4 e1 = *reinterpret_cast<const f32x4*>(&enc_s[m][dbase+4]);
      uint4v pk;
      pk[0] = pk2(tv*e0[0], tv*e0[1]);
      pk[1] = pk2(tv*e0[2], tv*e0[3]);
      pk[2] = pk2(tv*e1[0], tv*e1[1]);
      pk[3] = pk2(tv*e1[2], tv*e1[3]);
      short8 af = __builtin_bit_cast(short8, pk);
      const u16* bp = At + k0 + q*8;
      #pragma unroll
      for (int nt = 0; nt < 4; ++nt) {
        short8 bfv = *reinterpret_cast<const short8*>(bp + (nt*16 + m)*4096);
        acc[nt] = __builtin_amdgcn_mfma_f32_16x16x32_bf16(af, bfv, acc[nt], 0, 0, 0);
      }
    }
    #pragma unroll
    for (int nt = 0; nt < 4; ++nt)
      #pragma unroll
      for (int rg = 0; rg < 4; ++rg)
        red_s[w][q*4+rg][nt*16+m] = acc[nt][rg];   // D: row=q*4+reg, col=lane&15 (+nt*16)
    __syncthreads();                                  // (d)

    {
      u16* no = newa + (size_t)t*2048*64;
      const int c = tid & 63, r0 = tid >> 6;
      float s1 = 0.0f, s2 = 0.0f;
      #pragma unroll
      for (int rr = r0; rr < 16; rr += 8) {
        float v = red_s[0][rr][c] + red_s[1][rr][c] + red_s[2][rr][c] + red_s[3][rr][c]
                + red_s[4][rr][c] + red_s[5][rr][c] + red_s[6][rr][c] + red_s[7][rr][c];
        newf[rr][c] = v;
        no[(n0+rr)*64 + c] = f2bf(v);
        s1 += v; s2 = fmaf(v, v, s2);
      }
      sred[0][r0][c] = s1;
      sred[1][r0][c] = s2;
    }
    __syncthreads();                                  // (e)
    if (tid < 64) {
      float S1 = 0.0f, S2 = 0.0f;
      #pragma unroll
      for (int p = 0; p < 8; ++p) { S1 += sred[0][p][tid]; S2 += sred[1][p][tid]; }
      float* pb = part + (size_t)(t&1)*16384 + bid*128;
      __hip_atomic_store(pb + tid,      S1, __ATOMIC_RELAXED, __HIP_MEMORY_SCOPE_AGENT);
      __hip_atomic_store(pb + 64 + tid, S2, __ATOMIC_RELAXED, __HIP_MEMORY_SCOPE_AGENT);
    }
    __syncthreads();                                  // (f) stores drained (vmcnt in barrier)
    if (tid == 0)
      __hip_atomic_fetch_add(cnt + t, 1, __ATOMIC_RELEASE, __HIP_MEMORY_SCOPE_AGENT);
  }

  // epilogue: block 0 publishes stats[127] for phi
  if (bid == 0) {
    if (tid == 0) {
      while (__hip_atomic_load(cnt + 127, __ATOMIC_RELAXED, __HIP_MEMORY_SCOPE_AGENT) < 128)
        __builtin_amdgcn_s_sleep(2);
    }
    __syncthreads();
    __atomic_signal_fence(__ATOMIC_ACQUIRE);
    {
      const int e = tid & 127, pr = tid >> 7;
      const float* pb = part + (size_t)(127&1)*16384 + e;
      float s = 0.0f;
      #pragma unroll 8
      for (int p = pr*32; p < pr*32 + 32; ++p)
        s += __hip_atomic_load(pb + p*128, __ATOMIC_RELAXED, __HIP_MEMORY_SCOPE_AGENT);
      psum[pr][e] = s;
    }
    __syncthreads();
    if (tid < 128)
      stats[127*128 + tid] = psum[0][tid] + psum[1][tid] + psum[2][tid] + psum[3][tid];
  }
}

// ================= phi: parallel over (t, 32-row tiles); grid 8192 x 256 =================
__global__ __launch_bounds__(256) void phi_kernel(
    const u16* __restrict__ newa, const float* __restrict__ stats,
    const float* __restrict__ X,
    const u16* __restrict__ muWb, const u16* __restrict__ sigWb, const u16* __restrict__ alWb,
    const u16* __restrict__ muW2b, const u16* __restrict__ sigW2b, const u16* __restrict__ alW2b,
    const float* __restrict__ mub, const float* __restrict__ sigb, const float* __restrict__ alb,
    const float* __restrict__ mub2, const float* __restrict__ sigb2, const float* __restrict__ alb2,
    const float* __restrict__ bn_g, const float* __restrict__ bn_b,
    float* __restrict__ outp)
{
  __shared__ __align__(16) u16 h_s[32][72];
  __shared__ __align__(16) u16 smu[32][264];
  __shared__ __align__(16) u16 ssg[32][264];
  __shared__ __align__(16) u16 sal[32][40];
  __shared__ float xc_s[32][8];
  __shared__ float clp_s[32][32];
  __shared__ float alo_s[32][34];
  __shared__ float bias_s[1088];
  __shared__ float ab2[2][64];
  __shared__ float nrm_s[4];

  const int tid = threadIdx.x;
  const int bx = blockIdx.x;
  const int t  = bx & 127;
  const int n0 = (bx >> 7) * 32;
  const int lane = tid & 63, w = tid >> 6;
  const int m = lane & 15, q = lane >> 4;

  const u16*   na = newa + (size_t)t * 2048 * 64;
  const float* st = stats + t * 128;

  for (int e = tid; e < 1088; e += 256) {
    float v;
    if      (e < 256)  v = mub[e];
    else if (e < 512)  v = sigb[e-256];
    else if (e < 544)  v = alb[e-512];
    else if (e < 800)  v = mub2[e-544];
    else if (e < 1056) v = sigb2[e-800];
    else               v = alb2[e-1056];
    bias_s[e] = v;
  }
  if (tid < 64) {
    float mean = st[tid] * (1.0f/2048.0f);
    float var  = st[64+tid] * (1.0f/2048.0f) - mean*mean;
    float a = bn_g[tid] * rsqrtf(var + 1e-5f);
    ab2[0][tid] = a;
    ab2[1][tid] = fmaf(-a, mean, bn_b[tid]);
  }
  __syncthreads();

  // P1: tmp -> softmax h (bf16 LDS), norm partial, xc stage
  {
    const int r = tid >> 3, j8 = tid & 7;
    short8 nv = *reinterpret_cast<const short8*>(na + (n0+r)*64 + j8*8);
    float tv[8];
    float nacc = 0.0f, mx = -3.4e38f;
    #pragma unroll
    for (int j = 0; j < 8; ++j) {
      int i = j8*8 + j;
      float v = fmaf(ab2[0][i], bf2f((u16)nv[j]), ab2[1][i]);
      tv[j] = v;
      nacc = fmaf(v, v, nacc);
      mx = fmaxf(mx, v);
    }
    mx = fmaxf(mx, __shfl_xor(mx, 1));
    mx = fmaxf(mx, __shfl_xor(mx, 2));
    mx = fmaxf(mx, __shfl_xor(mx, 4));
    float se = 0.0f;
    #pragma unroll
    for (int j = 0; j < 8; ++j) { tv[j] = __expf(tv[j] - mx); se += tv[j]; }
    se += __shfl_xor(se, 1);
    se += __shfl_xor(se, 2);
    se += __shfl_xor(se, 4);
    float inv = 1.0f / se;
    #pragma unroll
    for (int j = 0; j < 8; ++j) h_s[r][j8*8+j] = f2bf(tv[j] * inv);
    nacc += __shfl_xor(nacc, 1);
    nacc += __shfl_xor(nacc, 2);
    nacc += __shfl_xor(nacc, 4);
    nacc += __shfl_xor(nacc, 8);
    nacc += __shfl_xor(nacc, 16);
    nacc += __shfl_xor(nacc, 32);
    if (lane == 0) nrm_s[w] = nacc;
    xc_s[r][j8] = X[(size_t)(n0+r)*1024 + j8*128 + t];
  }
  __syncthreads();

  // P2: layer-1 heads: waves 0,1 -> mu cols [0:128),[128:256); waves 2,3 -> sig; wave0 also al
  {
    const u16* W1 = (w < 2) ? muWb : sigWb;
    const int boff = (w < 2) ? 0 : 256;
    const int coloff = (w & 1) * 128;
    f32x4 acc[2][8];
    #pragma unroll
    for (int a_ = 0; a_ < 2; ++a_)
      #pragma unroll
      for (int b_ = 0; b_ < 8; ++b_) acc[a_][b_] = 0;
    #pragma unroll
    for (int mt = 0; mt < 2; ++mt)
      #pragma unroll
      for (int kit = 0; kit < 2; ++kit) {
        short8 af = *reinterpret_cast<const short8*>(&h_s[mt*16+m][kit*32 + q*8]);
        #pragma unroll
        for (int nt = 0; nt < 8; ++nt) {
          int c = coloff + nt*16 + m;
          short8 bfv = *reinterpret_cast<const short8*>(W1 + c*64 + kit*32 + q*8);
          acc[mt][nt] = __builtin_amdgcn_mfma_f32_16x16x32_bf16(af, bfv, acc[mt][nt], 0, 0, 0);
        }
      }
    #pragma unroll
    for (int mt = 0; mt < 2; ++mt)
      #pragma unroll
      for (int nt = 0; nt < 8; ++nt) {
        int col = coloff + nt*16 + m;
        float bia = bias_s[boff + col];
        #pragma unroll
        for (int rg = 0; rg < 4; ++rg) {
          int row = mt*16 + q*4 + rg;
          float v = acc[mt][nt][rg] + bia;
          v = v / (1.0f + fabsf(v));
          ((w < 2) ? smu : ssg)[row][col] = f2bf(v);
        }
      }
  }
  if (w == 0) {  // alpha layer-1
    f32x4 aacc[2][2];
    aacc[0][0] = 0; aacc[0][1] = 0; aacc[1][0] = 0; aacc[1][1] = 0;
    #pragma unroll
    for (int mt = 0; mt < 2; ++mt)
      #pragma unroll
      for (int kit = 0; kit < 2; ++kit) {
        short8 af = *reinterpret_cast<const short8*>(&h_s[mt*16+m][kit*32 + q*8]);
        #pragma unroll
        for (int nt = 0; nt < 2; ++nt) {
          short8 bfv = *reinterpret_cast<const short8*>(alWb + (nt*16+m)*64 + kit*32 + q*8);
          aacc[mt][nt] = __builtin_amdgcn_mfma_f32_16x16x32_bf16(af, bfv, aacc[mt][nt], 0, 0, 0);
        }
      }
    #pragma unroll
    for (int mt = 0; mt < 2; ++mt)
      #pragma unroll
      for (int nt = 0; nt < 2; ++nt) {
        int col = nt*16 + m;
        float bia = bias_s[512 + col];
        #pragma unroll
        for (int rg = 0; rg < 4; ++rg) {
          int row = mt*16 + q*4 + rg;
          float v = aacc[mt][nt][rg] + bia;
          v = v / (1.0f + fabsf(v));
          sal[row][col] = f2bf(v);
        }
      }
  }
  __syncthreads();

  // P3: layer-2 mu+sig GEMMs (wave w -> cols [64w,64w+64)) fused with GMM comp_lp; wave0: al2
  {
    #pragma unroll 1
    for (int mt = 0; mt < 2; ++mt) {
      f32x4 accm[4], accs[4];
      #pragma unroll
      for (int nt = 0; nt < 4; ++nt) { accm[nt] = 0; accs[nt] = 0; }
      for (int kit = 0; kit < 8; ++kit) {
        short8 am_ = *reinterpret_cast<const short8*>(&smu[mt*16+m][kit*32 + q*8]);
        short8 as_ = *reinterpret_cast<const short8*>(&ssg[mt*16+m][kit*32 + q*8]);
        #pragma unroll
        for (int nt = 0; nt < 4; ++nt) {
          int cb = w*64 + nt*16 + m;
          short8 bm = *reinterpret_cast<const short8*>(muW2b + cb*256 + kit*32 + q*8);
          short8 bs = *reinterpret_cast<const short8*>(sigW2b + cb*256 + kit*32 + q*8);
          accm[nt] = __builtin_amdgcn_mfma_f32_16x16x32_bf16(am_, bm, accm[nt], 0, 0, 0);
          accs[nt] = __builtin_amdgcn_mfma_f32_16x16x32_bf16(as_, bs, accs[nt], 0, 0, 0);
        }
      }
      #pragma unroll
      for (int nt = 0; nt < 4; ++nt) {
        int col = w*64 + nt*16 + m;
        int cmix = col >> 3, x = col & 7;
        float bmu = bias_s[544 + col], bsg = bias_s[800 + col];
        #pragma unroll
        for (int rg = 0; rg < 4; ++rg) {
          int row = mt*16 + q*4 + rg;
          float muv = accm[nt][rg] + bmu;
          float lsv = accs[nt][rg] + bsg;
          float z = (xc_s[row][x] - muv) * __expf(-lsv);
          float tt = fmaf(-0.5f*z, z, -lsv) - LOG2PI_HALF;
          tt += __shfl_xor(tt, 1);     // sum over x (lane bits 0..2)
          tt += __shfl_xor(tt, 2);
          tt += __shfl_xor(tt, 4);
          if (x == 0) clp_s[row][cmix] = tt;
        }
      }
    }
    if (w == 0) {  // alpha layer-2 (K=32 -> single MFMA K-step)
      #pragma unroll
      for (int mt = 0; mt < 2; ++mt) {
        f32x4 aacc[2]; aacc[0] = 0; aacc[1] = 0;
        short8 aa = *reinterpret_cast<const short8*>(&sal[mt*16+m][q*8]);
        #pragma unroll
        for (int nt = 0; nt < 2; ++nt) {
          short8 bb = *reinterpret_cast<const short8*>(alW2b + (nt*16+m)*32 + q*8);
          aacc[nt] = __builtin_amdgcn_mfma_f32_16x16x32_bf16(aa, bb, aacc[nt], 0, 0, 0);
        }
        #pragma unroll
        for (int nt = 0; nt < 2; ++nt) {
          int col = nt*16 + m;
          float bia = bias_s[1056 + col];
          #pragma unroll
          for (int rg = 0; rg < 4; ++rg)
            alo_s[mt*16 + q*4 + rg][col] = aacc[nt][rg] + bia;
        }
      }
    }
  }
  __syncthreads();

  // P5: log_softmax(alpha) + comp_lp -> logsumexp -> res; norm finalize
  {
    const int r = tid >> 3, jj = tid & 7;
    float av[4], am = -3.4e38f;
    #pragma unroll
    for (int u = 0; u < 4; ++u) { av[u] = alo_s[r][jj + u*8]; am = fmaxf(am, av[u]); }
    am = fmaxf(am, __shfl_xor(am, 1));
    am = fmaxf(am, __shfl_xor(am, 2));
    am = fmaxf(am, __shfl_xor(am, 4));
    float se = 0.0f;
    #pragma unroll
    for (int u = 0; u < 4; ++u) se += __expf(av[u] - am);
    se += __shfl_xor(se, 1);
    se += __shfl_xor(se, 2);
    se += __shfl_xor(se, 4);
    float la = am + __logf(se);
    float tt4[4], tm = -3.4e38f;
    #pragma unroll
    for (int u = 0; u < 4; ++u) {
      tt4[u] = av[u] - la + clp_s[r][jj + u*8];
      tm = fmaxf(tm, tt4[u]);
    }
    tm = fmaxf(tm, __shfl_xor(tm, 1));
    tm = fmaxf(tm, __shfl_xor(tm, 2));
    tm = fmaxf(tm, __shfl_xor(tm, 4));
    float ts = 0.0f;
    #pragma unroll
    for (int u = 0; u < 4; ++u) ts += __expf(tt4[u] - tm);
    ts += __shfl_xor(ts, 1);
    ts += __shfl_xor(ts, 2);
    ts += __shfl_xor(ts, 4);
    if (jj == 0) atomicAdd(&outp[n0 + r], tm + __logf(ts));
    if (tid == 0) atomicAdd(&outp[2048], nrm_s[0] + nrm_s[1] + nrm_s[2] + nrm_s[3]);
  }
}

extern "C" void kernel_launch(void* const* d_in, const int* in_sizes, int n_in,
                              void* d_out, int out_size, void* d_ws, size_t ws_size,
                              hipStream_t stream) {
  const float* X      = (const float*)d_in[0];
  const float* enc_w  = (const float*)d_in[1];
  const float* enc_b  = (const float*)d_in[2];
  const float* init_w = (const float*)d_in[3];
  const float* A      = (const float*)d_in[4];
  const float* bn_g   = (const float*)d_in[5];
  const float* bn_b   = (const float*)d_in[6];
  const float* muW    = (const float*)d_in[7];
  const float* mub    = (const float*)d_in[8];
  const float* muW2   = (const float*)d_in[9];
  const float* mub2   = (const float*)d_in[10];
  const float* sigW   = (const float*)d_in[11];
  const float* sigb   = (const float*)d_in[12];
  const float* sigW2  = (const float*)d_in[13];
  const float* sigb2  = (const float*)d_in[14];
  const float* alW    = (const float*)d_in[15];
  const float* alb    = (const float*)d_in[16];
  const float* alW2   = (const float*)d_in[17];
  const float* alb2   = (const float*)d_in[18];

  if (ws_size < WS_NEED) return;

  char* ws = (char*)d_ws;
  float* stats = (float*)(ws + OFF_STATS);
  u16* newa    = (u16*)(ws + OFF_NEW);
  u16* At      = (u16*)(ws + OFF_AT);
  u16* muWb    = (u16*)(ws + OFF_MUW);
  u16* sigWb   = (u16*)(ws + OFF_SIGW);
  u16* alWb    = (u16*)(ws + OFF_ALW);
  u16* muW2b   = (u16*)(ws + OFF_MUW2);
  u16* sigW2b  = (u16*)(ws + OFF_SIGW2);
  u16* alW2b   = (u16*)(ws + OFF_ALW2);
  int* cnt     = (int*)(ws + OFF_CNT);
  float* part  = (float*)(ws + OFF_PART);

  (void)hipMemsetAsync(d_out, 0, (size_t)out_size * sizeof(float), stream);
  (void)hipMemsetAsync(stats, 0, (size_t)128 * 128 * sizeof(float), stream);
  (void)hipMemsetAsync(cnt, 0, 512, stream);

  init_kernel<<<dim3(1024), dim3(256), 0, stream>>>(
      A, init_w, muW, sigW, alW, muW2, sigW2, alW2,
      At, newa, stats, muWb, sigWb, alWb, muW2b, sigW2b, alW2b);

  {
    u16* newa_a = newa; float* stats_a = stats; int* cnt_a = cnt; float* part_a = part;
    const float *X_a = X, *encw_a = enc_w, *encb_a = enc_b, *bng_a = bn_g, *bnb_a = bn_b, *initw_a = init_w;
    const u16* At_a = At;
    void* args[] = { (void*)&newa_a, (void*)&stats_a, (void*)&cnt_a, (void*)&part_a, (void*)&X_a,
                     (void*)&encw_a, (void*)&encb_a, (void*)&bng_a, (void*)&bnb_a, (void*)&At_a, (void*)&initw_a };
    (void)hipLaunchCooperativeKernel((void*)chain_kernel, dim3(128), dim3(512), args, 0, stream);
  }

  phi_kernel<<<dim3(8192), dim3(256), 0, stream>>>(
      newa, stats, X,
      muWb, sigWb, alWb, muW2b, sigW2b, alW2b,
      mub, sigb, alb, mub2, sigb2, alb2,
      bn_g, bn_b, (float*)d_out);
}

// Round 6
// 2989.490 us; speedup vs baseline: 1.5053x; 1.1305x over previous
//
#include <hip/hip_runtime.h>

typedef unsigned short u16;
typedef short short8 __attribute__((ext_vector_type(8)));
typedef float f32x4 __attribute__((ext_vector_type(4)));
typedef unsigned uint4v __attribute__((ext_vector_type(4)));

#define LOG2PI_HALF 0.91893853320467274f

// ---- workspace layout (bytes) ----
static constexpr size_t OFF_STATS = 0;                                  // [128][2][64] f32
static constexpr size_t OFF_NEW   = 65536;                              // [128][2048][64] bf16
static constexpr size_t OFF_AT    = OFF_NEW + (size_t)128*2048*64*2;    // [64][4096] bf16 (A^T)
static constexpr size_t OFF_MUW   = OFF_AT   + (size_t)64*4096*2;
static constexpr size_t OFF_SIGW  = OFF_MUW  + (size_t)256*64*2;
static constexpr size_t OFF_ALW   = OFF_SIGW + (size_t)256*64*2;
static constexpr size_t OFF_MUW2  = OFF_ALW  + (size_t)32*64*2;
static constexpr size_t OFF_SIGW2 = OFF_MUW2 + (size_t)256*256*2;
static constexpr size_t OFF_ALW2  = OFF_SIGW2+ (size_t)256*256*2;
static constexpr size_t OFF_CNT   = OFF_ALW2 + (size_t)32*32*2;         // [128] int epoch flags
static constexpr size_t OFF_PART  = OFF_CNT + 512;                      // [2][128][128] f32 partial stats
static constexpr size_t WS_NEED   = OFF_PART + (size_t)2*128*128*4;

static __device__ __forceinline__ u16 f2bf(float x) {
  unsigned u = __builtin_bit_cast(unsigned, x);
  u += 0x7fffu + ((u >> 16) & 1u);          // RNE
  return (u16)(u >> 16);
}
static __device__ __forceinline__ float bf2f(u16 b) {
  unsigned u = ((unsigned)b) << 16;
  return __builtin_bit_cast(float, u);
}
static __device__ __forceinline__ unsigned pk2(float a, float b) {
  return ((unsigned)f2bf(b) << 16) | (unsigned)f2bf(a);
}

// ================= init: convert A^T + weights to bf16, seed step 0 =================
__global__ void init_kernel(
    const float* __restrict__ A, const float* __restrict__ init_w,
    const float* __restrict__ muW, const float* __restrict__ sigW, const float* __restrict__ alW,
    const float* __restrict__ muW2, const float* __restrict__ sigW2, const float* __restrict__ alW2,
    u16* __restrict__ At, u16* __restrict__ new0, float* __restrict__ stats0,
    u16* __restrict__ muWb, u16* __restrict__ sigWb, u16* __restrict__ alWb,
    u16* __restrict__ muW2b, u16* __restrict__ sigW2b, u16* __restrict__ alW2b)
{
  const int total = 560192;
  for (int idx = blockIdx.x*256 + threadIdx.x; idx < total; idx += gridDim.x*256) {
    if (idx < 262144) {                       // At[j][k] = A[k][j], Aflat[k][j]=A[i,d,j], k=i*64+d
      int j = idx >> 12, k = idx & 4095;
      At[idx] = f2bf(A[k*64 + j]);
    } else if (idx < 393216) {                // new_all[0][n][i] = bf16(init_w[i])
      int e = idx - 262144;
      new0[e] = f2bf(init_w[e & 63]);
    } else if (idx < 409600) { int e = idx - 393216; muWb[e]   = f2bf(muW[e]);
    } else if (idx < 425984) { int e = idx - 409600; sigWb[e]  = f2bf(sigW[e]);
    } else if (idx < 428032) { int e = idx - 425984; alWb[e]   = f2bf(alW[e]);
    } else if (idx < 493568) { int e = idx - 428032; muW2b[e]  = f2bf(muW2[e]);
    } else if (idx < 559104) { int e = idx - 493568; sigW2b[e] = f2bf(sigW2[e]);
    } else if (idx < 560128) { int e = idx - 559104; alW2b[e]  = f2bf(alW2[e]);
    } else {                                  // stats[0]: match stored bf16 values exactly -> var==0
      int e = idx - 560128;
      float wv = bf2f(f2bf(init_w[e]));
      stats0[e]      = 2048.0f * wv;
      stats0[64 + e] = 2048.0f * (wv * wv);
    }
  }
}

// ============ persistent chain: 127 steps; epoch-flag barrier (no RMW, no wbl2) ============
// 128 blk x 512 thr; block owns 16 rows; new kept in LDS f32; waves split K 8-way.
__global__ __launch_bounds__(512) void chain_kernel(
    u16* __restrict__ newa, float* stats, int* flags, float* part,
    const float* __restrict__ X,
    const float* __restrict__ enc_w, const float* __restrict__ enc_b,
    const float* __restrict__ bn_g, const float* __restrict__ bn_b,
    const u16* __restrict__ At, const float* __restrict__ init_w)
{
  __shared__ float newf[16][64];
  __shared__ __align__(16) float tmp_s[16][66];
  __shared__ __align__(16) float enc_s[16][68];
  __shared__ float xp_s[16][8];
  __shared__ float ab_s[2][64];
  __shared__ float psum[4][128];
  __shared__ float red_s[8][16][64];
  __shared__ float sred[2][8][64];

  const int tid = threadIdx.x;
  const int bid = blockIdx.x;
  const int n0  = bid * 16;
  const int lane = tid & 63, w = tid >> 6;
  const int m = lane & 15, q = lane >> 4;

  // seed new_0 = bf16-rounded init_w (matches init_kernel's new0/stats0 exactly)
  for (int e = tid; e < 1024; e += 512) {
    int r = e >> 6, c = e & 63;
    newf[r][c] = bf2f(f2bf(init_w[c]));
  }

  for (int t = 1; t < 128; ++t) {
    if (tid < 128) {
      int r = tid >> 3, k = tid & 7;
      xp_s[r][k] = X[(size_t)(n0+r)*1024 + k*128 + (t-1)];
    }
    __syncthreads();                                  // (a) xp visible
    // enc = softsign(xp @ enc_w.T + enc_b)  -- independent of stats
    {
      int r = tid >> 5, d0 = (tid & 31) * 2;
      #pragma unroll
      for (int dd = 0; dd < 2; ++dd) {
        int d = d0 + dd;
        float a = enc_b[d];
        #pragma unroll
        for (int k = 0; k < 8; ++k) a = fmaf(xp_s[r][k], enc_w[d*8+k], a);
        enc_s[r][d] = a / (1.0f + fabsf(a));
      }
    }

    if (t >= 2) {
      // epoch-flag wait: plain relaxed loads (no invalidation), no RMW counter
      if (w == 0) {
        for (;;) {
          int v0 = __hip_atomic_load(flags + lane*2,     __ATOMIC_RELAXED, __HIP_MEMORY_SCOPE_AGENT);
          int v1 = __hip_atomic_load(flags + lane*2 + 1, __ATOMIC_RELAXED, __HIP_MEMORY_SCOPE_AGENT);
          if (__ballot((v0 >= t-1) && (v1 >= t-1)) == ~0ull) break;
          __builtin_amdgcn_s_sleep(1);
        }
      }
      __syncthreads();                                // (a2) all waves past wait
      __atomic_signal_fence(__ATOMIC_ACQUIRE);
      // reduce 128 per-block partials (sc1 loads read LLC directly)
      {
        const int e = tid & 127, pr = tid >> 7;       // pr in [0,4)
        const float* pb = part + (size_t)((t-1)&1)*16384 + e;
        float s = 0.0f;
        #pragma unroll 16
        for (int p = pr*32; p < pr*32 + 32; ++p)
          s += __hip_atomic_load(pb + p*128, __ATOMIC_RELAXED, __HIP_MEMORY_SCOPE_AGENT);
        psum[pr][e] = s;
      }
      __syncthreads();                                // (b1) psum visible
      if (bid == 0 && tid < 128)                      // publish stats[t-1] for phi
        stats[(t-1)*128 + tid] = psum[0][tid] + psum[1][tid] + psum[2][tid] + psum[3][tid];
      if (tid < 64) {
        float S1 = psum[0][tid] + psum[1][tid] + psum[2][tid] + psum[3][tid];
        float S2 = psum[0][tid+64] + psum[1][tid+64] + psum[2][tid+64] + psum[3][tid+64];
        float mean = S1 * (1.0f/2048.0f);
        float var  = S2 * (1.0f/2048.0f) - mean*mean;
        float a = bn_g[tid] * rsqrtf(var + 1e-5f);
        ab_s[0][tid] = a;
        ab_s[1][tid] = fmaf(-a, mean, bn_b[tid]);
      }
    } else {
      if (tid < 64) {
        float mean = bf2f(f2bf(init_w[tid]));
        float a = bn_g[tid] * rsqrtf(1e-5f);
        ab_s[0][tid] = a;
        ab_s[1][tid] = fmaf(-a, mean, bn_b[tid]);
      }
    }
    __syncthreads();                                  // (b2) ab_s + enc_s visible

    // tmp = a*new + b
    #pragma unroll
    for (int e0 = 0; e0 < 1024; e0 += 512) {
      int e = e0 + tid;
      int mr = e >> 6, i = e & 63;
      tmp_s[mr][i] = fmaf(ab_s[0][i], newf[mr][i], ab_s[1][i]);
    }
    __syncthreads();                                  // (c) tmp visible

    f32x4 acc[4];
    #pragma unroll
    for (int nt = 0; nt < 4; ++nt) acc[nt] = 0;

    #pragma unroll 4
    for (int it = 0; it < 16; ++it) {
      const int k0 = w*512 + it*32;
      const int i = k0 >> 6;
      const int dbase = (k0 & 63) + q*8;
      const float tv = tmp_s[m][i];
      const f32x4 e0 = *reinterpret_cast<const f32x4*>(&enc_s[m][dbase]);
      const f32x4 e1 = *reinterpret_cast<const f32x4*>(&enc_s[m][dbase+4]);
      uint4v pk;
      pk[0] = pk2(tv*e0[0], tv*e0[1]);
      pk[1] = pk2(tv*e0[2], tv*e0[3]);
      pk[2] = pk2(tv*e1[0], tv*e1[1]);
      pk[3] = pk2(tv*e1[2], tv*e1[3]);
      short8 af = __builtin_bit_cast(short8, pk);
      const u16* bp = At + k0 + q*8;
      #pragma unroll
      for (int nt = 0; nt < 4; ++nt) {
        short8 bfv = *reinterpret_cast<const short8*>(bp + (nt*16 + m)*4096);
        acc[nt] = __builtin_amdgcn_mfma_f32_16x16x32_bf16(af, bfv, acc[nt], 0, 0, 0);
      }
    }
    #pragma unroll
    for (int nt = 0; nt < 4; ++nt)
      #pragma unroll
      for (int rg = 0; rg < 4; ++rg)
        red_s[w][q*4+rg][nt*16+m] = acc[nt][rg];   // D: row=q*4+reg, col=lane&15 (+nt*16)
    __syncthreads();                                  // (d)

    {
      u16* no = newa + (size_t)t*2048*64;
      const int c = tid & 63, r0 = tid >> 6;
      float s1 = 0.0f, s2 = 0.0f;
      #pragma unroll
      for (int rr = r0; rr < 16; rr += 8) {
        float v = red_s[0][rr][c] + red_s[1][rr][c] + red_s[2][rr][c] + red_s[3][rr][c]
                + red_s[4][rr][c] + red_s[5][rr][c] + red_s[6][rr][c] + red_s[7][rr][c];
        newf[rr][c] = v;
        no[(n0+rr)*64 + c] = f2bf(v);
        s1 += v; s2 = fmaf(v, v, s2);
      }
      sred[0][r0][c] = s1;
      sred[1][r0][c] = s2;
    }
    __syncthreads();                                  // (e)
    if (tid < 64) {
      float S1 = 0.0f, S2 = 0.0f;
      #pragma unroll
      for (int p = 0; p < 8; ++p) { S1 += sred[0][p][tid]; S2 += sred[1][p][tid]; }
      float* pb = part + (size_t)(t&1)*16384 + bid*128;
      __hip_atomic_store(pb + tid,      S1, __ATOMIC_RELAXED, __HIP_MEMORY_SCOPE_AGENT);
      __hip_atomic_store(pb + 64 + tid, S2, __ATOMIC_RELAXED, __HIP_MEMORY_SCOPE_AGENT);
    }
    __syncthreads();          // (f) wave0's sc1 part-stores drained (s_waitcnt vmcnt(0) in barrier)
    if (tid == 0)             // epoch publish: plain relaxed sc1 store -- no RMW, no wbl2
      __hip_atomic_store(flags + bid, t, __ATOMIC_RELAXED, __HIP_MEMORY_SCOPE_AGENT);
  }

  // epilogue: block 0 publishes stats[127] for phi
  if (bid == 0) {
    if (w == 0) {
      for (;;) {
        int v0 = __hip_atomic_load(flags + lane*2,     __ATOMIC_RELAXED, __HIP_MEMORY_SCOPE_AGENT);
        int v1 = __hip_atomic_load(flags + lane*2 + 1, __ATOMIC_RELAXED, __HIP_MEMORY_SCOPE_AGENT);
        if (__ballot((v0 >= 127) && (v1 >= 127)) == ~0ull) break;
        __builtin_amdgcn_s_sleep(1);
      }
    }
    __syncthreads();
    __atomic_signal_fence(__ATOMIC_ACQUIRE);
    {
      const int e = tid & 127, pr = tid >> 7;
      const float* pb = part + (size_t)(127&1)*16384 + e;
      float s = 0.0f;
      #pragma unroll 16
      for (int p = pr*32; p < pr*32 + 32; ++p)
        s += __hip_atomic_load(pb + p*128, __ATOMIC_RELAXED, __HIP_MEMORY_SCOPE_AGENT);
      psum[pr][e] = s;
    }
    __syncthreads();
    if (tid < 128)
      stats[127*128 + tid] = psum[0][tid] + psum[1][tid] + psum[2][tid] + psum[3][tid];
  }
}

// ================= phi: parallel over (t, 32-row tiles); grid 8192 x 256 =================
__global__ __launch_bounds__(256) void phi_kernel(
    const u16* __restrict__ newa, const float* __restrict__ stats,
    const float* __restrict__ X,
    const u16* __restrict__ muWb, const u16* __restrict__ sigWb, const u16* __restrict__ alWb,
    const u16* __restrict__ muW2b, const u16* __restrict__ sigW2b, const u16* __restrict__ alW2b,
    const float* __restrict__ mub, const float* __restrict__ sigb, const float* __restrict__ alb,
    const float* __restrict__ mub2, const float* __restrict__ sigb2, const float* __restrict__ alb2,
    const float* __restrict__ bn_g, const float* __restrict__ bn_b,
    float* __restrict__ outp)
{
  __shared__ __align__(16) u16 h_s[32][72];
  __shared__ __align__(16) u16 smu[32][264];
  __shared__ __align__(16) u16 ssg[32][264];
  __shared__ __align__(16) u16 sal[32][40];
  __shared__ float xc_s[32][8];
  __shared__ float clp_s[32][32];
  __shared__ float alo_s[32][34];
  __shared__ float bias_s[1088];
  __shared__ float ab2[2][64];
  __shared__ float nrm_s[4];

  const int tid = threadIdx.x;
  const int bx = blockIdx.x;
  const int t  = bx & 127;
  const int n0 = (bx >> 7) * 32;
  const int lane = tid & 63, w = tid >> 6;
  const int m = lane & 15, q = lane >> 4;

  const u16*   na = newa + (size_t)t * 2048 * 64;
  const float* st = stats + t * 128;

  for (int e = tid; e < 1088; e += 256) {
    float v;
    if      (e < 256)  v = mub[e];
    else if (e < 512)  v = sigb[e-256];
    else if (e < 544)  v = alb[e-512];
    else if (e < 800)  v = mub2[e-544];
    else if (e < 1056) v = sigb2[e-800];
    else               v = alb2[e-1056];
    bias_s[e] = v;
  }
  if (tid < 64) {
    float mean = st[tid] * (1.0f/2048.0f);
    float var  = st[64+tid] * (1.0f/2048.0f) - mean*mean;
    float a = bn_g[tid] * rsqrtf(var + 1e-5f);
    ab2[0][tid] = a;
    ab2[1][tid] = fmaf(-a, mean, bn_b[tid]);
  }
  __syncthreads();

  // P1: tmp -> softmax h (bf16 LDS), norm partial, xc stage
  {
    const int r = tid >> 3, j8 = tid & 7;
    short8 nv = *reinterpret_cast<const short8*>(na + (n0+r)*64 + j8*8);
    float tv[8];
    float nacc = 0.0f, mx = -3.4e38f;
    #pragma unroll
    for (int j = 0; j < 8; ++j) {
      int i = j8*8 + j;
      float v = fmaf(ab2[0][i], bf2f((u16)nv[j]), ab2[1][i]);
      tv[j] = v;
      nacc = fmaf(v, v, nacc);
      mx = fmaxf(mx, v);
    }
    mx = fmaxf(mx, __shfl_xor(mx, 1));
    mx = fmaxf(mx, __shfl_xor(mx, 2));
    mx = fmaxf(mx, __shfl_xor(mx, 4));
    float se = 0.0f;
    #pragma unroll
    for (int j = 0; j < 8; ++j) { tv[j] = __expf(tv[j] - mx); se += tv[j]; }
    se += __shfl_xor(se, 1);
    se += __shfl_xor(se, 2);
    se += __shfl_xor(se, 4);
    float inv = 1.0f / se;
    #pragma unroll
    for (int j = 0; j < 8; ++j) h_s[r][j8*8+j] = f2bf(tv[j] * inv);
    nacc += __shfl_xor(nacc, 1);
    nacc += __shfl_xor(nacc, 2);
    nacc += __shfl_xor(nacc, 4);
    nacc += __shfl_xor(nacc, 8);
    nacc += __shfl_xor(nacc, 16);
    nacc += __shfl_xor(nacc, 32);
    if (lane == 0) nrm_s[w] = nacc;
    xc_s[r][j8] = X[(size_t)(n0+r)*1024 + j8*128 + t];
  }
  __syncthreads();

  // P2: layer-1 heads: waves 0,1 -> mu cols [0:128),[128:256); waves 2,3 -> sig; wave0 also al
  {
    const u16* W1 = (w < 2) ? muWb : sigWb;
    const int boff = (w < 2) ? 0 : 256;
    const int coloff = (w & 1) * 128;
    f32x4 acc[2][8];
    #pragma unroll
    for (int a_ = 0; a_ < 2; ++a_)
      #pragma unroll
      for (int b_ = 0; b_ < 8; ++b_) acc[a_][b_] = 0;
    #pragma unroll
    for (int mt = 0; mt < 2; ++mt)
      #pragma unroll
      for (int kit = 0; kit < 2; ++kit) {
        short8 af = *reinterpret_cast<const short8*>(&h_s[mt*16+m][kit*32 + q*8]);
        #pragma unroll
        for (int nt = 0; nt < 8; ++nt) {
          int c = coloff + nt*16 + m;
          short8 bfv = *reinterpret_cast<const short8*>(W1 + c*64 + kit*32 + q*8);
          acc[mt][nt] = __builtin_amdgcn_mfma_f32_16x16x32_bf16(af, bfv, acc[mt][nt], 0, 0, 0);
        }
      }
    #pragma unroll
    for (int mt = 0; mt < 2; ++mt)
      #pragma unroll
      for (int nt = 0; nt < 8; ++nt) {
        int col = coloff + nt*16 + m;
        float bia = bias_s[boff + col];
        #pragma unroll
        for (int rg = 0; rg < 4; ++rg) {
          int row = mt*16 + q*4 + rg;
          float v = acc[mt][nt][rg] + bia;
          v = v / (1.0f + fabsf(v));
          ((w < 2) ? smu : ssg)[row][col] = f2bf(v);
        }
      }
  }
  if (w == 0) {  // alpha layer-1
    f32x4 aacc[2][2];
    aacc[0][0] = 0; aacc[0][1] = 0; aacc[1][0] = 0; aacc[1][1] = 0;
    #pragma unroll
    for (int mt = 0; mt < 2; ++mt)
      #pragma unroll
      for (int kit = 0; kit < 2; ++kit) {
        short8 af = *reinterpret_cast<const short8*>(&h_s[mt*16+m][kit*32 + q*8]);
        #pragma unroll
        for (int nt = 0; nt < 2; ++nt) {
          short8 bfv = *reinterpret_cast<const short8*>(alWb + (nt*16+m)*64 + kit*32 + q*8);
          aacc[mt][nt] = __builtin_amdgcn_mfma_f32_16x16x32_bf16(af, bfv, aacc[mt][nt], 0, 0, 0);
        }
      }
    #pragma unroll
    for (int mt = 0; mt < 2; ++mt)
      #pragma unroll
      for (int nt = 0; nt < 2; ++nt) {
        int col = nt*16 + m;
        float bia = bias_s[512 + col];
        #pragma unroll
        for (int rg = 0; rg < 4; ++rg) {
          int row = mt*16 + q*4 + rg;
          float v = aacc[mt][nt][rg] + bia;
          v = v / (1.0f + fabsf(v));
          sal[row][col] = f2bf(v);
        }
      }
  }
  __syncthreads();

  // P3: layer-2 mu+sig GEMMs (wave w -> cols [64w,64w+64)) fused with GMM comp_lp; wave0: al2
  {
    #pragma unroll 1
    for (int mt = 0; mt < 2; ++mt) {
      f32x4 accm[4], accs[4];
      #pragma unroll
      for (int nt = 0; nt < 4; ++nt) { accm[nt] = 0; accs[nt] = 0; }
      for (int kit = 0; kit < 8; ++kit) {
        short8 am_ = *reinterpret_cast<const short8*>(&smu[mt*16+m][kit*32 + q*8]);
        short8 as_ = *reinterpret_cast<const short8*>(&ssg[mt*16+m][kit*32 + q*8]);
        #pragma unroll
        for (int nt = 0; nt < 4; ++nt) {
          int cb = w*64 + nt*16 + m;
          short8 bm = *reinterpret_cast<const short8*>(muW2b + cb*256 + kit*32 + q*8);
          short8 bs = *reinterpret_cast<const short8*>(sigW2b + cb*256 + kit*32 + q*8);
          accm[nt] = __builtin_amdgcn_mfma_f32_16x16x32_bf16(am_, bm, accm[nt], 0, 0, 0);
          accs[nt] = __builtin_amdgcn_mfma_f32_16x16x32_bf16(as_, bs, accs[nt], 0, 0, 0);
        }
      }
      #pragma unroll
      for (int nt = 0; nt < 4; ++nt) {
        int col = w*64 + nt*16 + m;
        int cmix = col >> 3, x = col & 7;
        float bmu = bias_s[544 + col], bsg = bias_s[800 + col];
        #pragma unroll
        for (int rg = 0; rg < 4; ++rg) {
          int row = mt*16 + q*4 + rg;
          float muv = accm[nt][rg] + bmu;
          float lsv = accs[nt][rg] + bsg;
          float z = (xc_s[row][x] - muv) * __expf(-lsv);
          float tt = fmaf(-0.5f*z, z, -lsv) - LOG2PI_HALF;
          tt += __shfl_xor(tt, 1);     // sum over x (lane bits 0..2)
          tt += __shfl_xor(tt, 2);
          tt += __shfl_xor(tt, 4);
          if (x == 0) clp_s[row][cmix] = tt;
        }
      }
    }
    if (w == 0) {  // alpha layer-2 (K=32 -> single MFMA K-step)
      #pragma unroll
      for (int mt = 0; mt < 2; ++mt) {
        f32x4 aacc[2]; aacc[0] = 0; aacc[1] = 0;
        short8 aa = *reinterpret_cast<const short8*>(&sal[mt*16+m][q*8]);
        #pragma unroll
        for (int nt = 0; nt < 2; ++nt) {
          short8 bb = *reinterpret_cast<const short8*>(alW2b + (nt*16+m)*32 + q*8);
          aacc[nt] = __builtin_amdgcn_mfma_f32_16x16x32_bf16(aa, bb, aacc[nt], 0, 0, 0);
        }
        #pragma unroll
        for (int nt = 0; nt < 2; ++nt) {
          int col = nt*16 + m;
          float bia = bias_s[1056 + col];
          #pragma unroll
          for (int rg = 0; rg < 4; ++rg)
            alo_s[mt*16 + q*4 + rg][col] = aacc[nt][rg] + bia;
        }
      }
    }
  }
  __syncthreads();

  // P5: log_softmax(alpha) + comp_lp -> logsumexp -> res; norm finalize
  {
    const int r = tid >> 3, jj = tid & 7;
    float av[4], am = -3.4e38f;
    #pragma unroll
    for (int u = 0; u < 4; ++u) { av[u] = alo_s[r][jj + u*8]; am = fmaxf(am, av[u]); }
    am = fmaxf(am, __shfl_xor(am, 1));
    am = fmaxf(am, __shfl_xor(am, 2));
    am = fmaxf(am, __shfl_xor(am, 4));
    float se = 0.0f;
    #pragma unroll
    for (int u = 0; u < 4; ++u) se += __expf(av[u] - am);
    se += __shfl_xor(se, 1);
    se += __shfl_xor(se, 2);
    se += __shfl_xor(se, 4);
    float la = am + __logf(se);
    float tt4[4], tm = -3.4e38f;
    #pragma unroll
    for (int u = 0; u < 4; ++u) {
      tt4[u] = av[u] - la + clp_s[r][jj + u*8];
      tm = fmaxf(tm, tt4[u]);
    }
    tm = fmaxf(tm, __shfl_xor(tm, 1));
    tm = fmaxf(tm, __shfl_xor(tm, 2));
    tm = fmaxf(tm, __shfl_xor(tm, 4));
    float ts = 0.0f;
    #pragma unroll
    for (int u = 0; u < 4; ++u) ts += __expf(tt4[u] - tm);
    ts += __shfl_xor(ts, 1);
    ts += __shfl_xor(ts, 2);
    ts += __shfl_xor(ts, 4);
    if (jj == 0) atomicAdd(&outp[n0 + r], tm + __logf(ts));
    if (tid == 0) atomicAdd(&outp[2048], nrm_s[0] + nrm_s[1] + nrm_s[2] + nrm_s[3]);
  }
}

extern "C" void kernel_launch(void* const* d_in, const int* in_sizes, int n_in,
                              void* d_out, int out_size, void* d_ws, size_t ws_size,
                              hipStream_t stream) {
  const float* X      = (const float*)d_in[0];
  const float* enc_w  = (const float*)d_in[1];
  const float* enc_b  = (const float*)d_in[2];
  const float* init_w = (const float*)d_in[3];
  const float* A      = (const float*)d_in[4];
  const float* bn_g   = (const float*)d_in[5];
  const float* bn_b   = (const float*)d_in[6];
  const float* muW    = (const float*)d_in[7];
  const float* mub    = (const float*)d_in[8];
  const float* muW2   = (const float*)d_in[9];
  const float* mub2   = (const float*)d_in[10];
  const float* sigW   = (const float*)d_in[11];
  const float* sigb   = (const float*)d_in[12];
  const float* sigW2  = (const float*)d_in[13];
  const float* sigb2  = (const float*)d_in[14];
  const float* alW    = (const float*)d_in[15];
  const float* alb    = (const float*)d_in[16];
  const float* alW2   = (const float*)d_in[17];
  const float* alb2   = (const float*)d_in[18];

  if (ws_size < WS_NEED) return;

  char* ws = (char*)d_ws;
  float* stats = (float*)(ws + OFF_STATS);
  u16* newa    = (u16*)(ws + OFF_NEW);
  u16* At      = (u16*)(ws + OFF_AT);
  u16* muWb    = (u16*)(ws + OFF_MUW);
  u16* sigWb   = (u16*)(ws + OFF_SIGW);
  u16* alWb    = (u16*)(ws + OFF_ALW);
  u16* muW2b   = (u16*)(ws + OFF_MUW2);
  u16* sigW2b  = (u16*)(ws + OFF_SIGW2);
  u16* alW2b   = (u16*)(ws + OFF_ALW2);
  int* flags   = (int*)(ws + OFF_CNT);
  float* part  = (float*)(ws + OFF_PART);

  (void)hipMemsetAsync(d_out, 0, (size_t)out_size * sizeof(float), stream);
  (void)hipMemsetAsync(stats, 0, (size_t)128 * 128 * sizeof(float), stream);
  (void)hipMemsetAsync(flags, 0, 512, stream);

  init_kernel<<<dim3(1024), dim3(256), 0, stream>>>(
      A, init_w, muW, sigW, alW, muW2, sigW2, alW2,
      At, newa, stats, muWb, sigWb, alWb, muW2b, sigW2b, alW2b);

  {
    u16* newa_a = newa; float* stats_a = stats; int* flags_a = flags; float* part_a = part;
    const float *X_a = X, *encw_a = enc_w, *encb_a = enc_b, *bng_a = bn_g, *bnb_a = bn_b, *initw_a = init_w;
    const u16* At_a = At;
    void* args[] = { (void*)&newa_a, (void*)&stats_a, (void*)&flags_a, (void*)&part_a, (void*)&X_a,
                     (void*)&encw_a, (void*)&encb_a, (void*)&bng_a, (void*)&bnb_a, (void*)&At_a, (void*)&initw_a };
    (void)hipLaunchCooperativeKernel((void*)chain_kernel, dim3(128), dim3(512), args, 0, stream);
  }

  phi_kernel<<<dim3(8192), dim3(256), 0, stream>>>(
      newa, stats, X,
      muWb, sigWb, alWb, muW2b, sigW2b, alW2b,
      mub, sigb, alb, mub2, sigb2, alb2,
      bn_g, bn_b, (float*)d_out);
}

// Round 7
// 2377.165 us; speedup vs baseline: 1.8930x; 1.2576x over previous
//
#include <hip/hip_runtime.h>

typedef unsigned short u16;
typedef short short8 __attribute__((ext_vector_type(8)));
typedef float f32x4 __attribute__((ext_vector_type(4)));
typedef unsigned uint4v __attribute__((ext_vector_type(4)));

#define LOG2PI_HALF 0.91893853320467274f
#define AO __ATOMIC_RELAXED
#define AS __HIP_MEMORY_SCOPE_AGENT

// ---- workspace layout (bytes) ----
static constexpr size_t OFF_STATS = 0;                                  // [128][2][64] f32
static constexpr size_t OFF_NEW   = 65536;                              // [128][2048][64] bf16
static constexpr size_t OFF_AT    = OFF_NEW + (size_t)128*2048*64*2;    // [64][4096] bf16 (A^T)
static constexpr size_t OFF_MUW   = OFF_AT   + (size_t)64*4096*2;
static constexpr size_t OFF_SIGW  = OFF_MUW  + (size_t)256*64*2;
static constexpr size_t OFF_ALW   = OFF_SIGW + (size_t)256*64*2;
static constexpr size_t OFF_MUW2  = OFF_ALW  + (size_t)32*64*2;
static constexpr size_t OFF_SIGW2 = OFF_MUW2 + (size_t)256*256*2;
static constexpr size_t OFF_ALW2  = OFF_SIGW2+ (size_t)256*256*2;
static constexpr size_t OFF_CNT   = OFF_ALW2 + (size_t)32*32*2;         // [128] epochs + [1] sflag
static constexpr size_t OFF_PART  = OFF_CNT + 1024;                     // [2][128][128] f32 partials
static constexpr size_t WS_NEED   = OFF_PART + (size_t)2*128*128*4;

static __device__ __forceinline__ u16 f2bf(float x) {
  unsigned u = __builtin_bit_cast(unsigned, x);
  u += 0x7fffu + ((u >> 16) & 1u);          // RNE
  return (u16)(u >> 16);
}
static __device__ __forceinline__ float bf2f(u16 b) {
  unsigned u = ((unsigned)b) << 16;
  return __builtin_bit_cast(float, u);
}
static __device__ __forceinline__ unsigned pk2(float a, float b) {
  return ((unsigned)f2bf(b) << 16) | (unsigned)f2bf(a);
}

// ================= init: convert A^T + weights to bf16, seed step 0 =================
__global__ void init_kernel(
    const float* __restrict__ A, const float* __restrict__ init_w,
    const float* __restrict__ muW, const float* __restrict__ sigW, const float* __restrict__ alW,
    const float* __restrict__ muW2, const float* __restrict__ sigW2, const float* __restrict__ alW2,
    u16* __restrict__ At, u16* __restrict__ new0, float* __restrict__ stats0,
    u16* __restrict__ muWb, u16* __restrict__ sigWb, u16* __restrict__ alWb,
    u16* __restrict__ muW2b, u16* __restrict__ sigW2b, u16* __restrict__ alW2b)
{
  const int total = 560192;
  for (int idx = blockIdx.x*256 + threadIdx.x; idx < total; idx += gridDim.x*256) {
    if (idx < 262144) {                       // At[j][k] = A[k][j]
      int j = idx >> 12, k = idx & 4095;
      At[idx] = f2bf(A[k*64 + j]);
    } else if (idx < 393216) {
      int e = idx - 262144;
      new0[e] = f2bf(init_w[e & 63]);
    } else if (idx < 409600) { int e = idx - 393216; muWb[e]   = f2bf(muW[e]);
    } else if (idx < 425984) { int e = idx - 409600; sigWb[e]  = f2bf(sigW[e]);
    } else if (idx < 428032) { int e = idx - 425984; alWb[e]   = f2bf(alW[e]);
    } else if (idx < 493568) { int e = idx - 428032; muW2b[e]  = f2bf(muW2[e]);
    } else if (idx < 559104) { int e = idx - 493568; sigW2b[e] = f2bf(sigW2[e]);
    } else if (idx < 560128) { int e = idx - 559104; alW2b[e]  = f2bf(alW2[e]);
    } else {
      int e = idx - 560128;
      float wv = bf2f(f2bf(init_w[e]));
      stats0[e]      = 2048.0f * wv;
      stats0[64 + e] = 2048.0f * (wv * wv);
    }
  }
}

struct ChainS {
  float newf[16][64];
  float tmp_s[16][66];
  float enc_s[16][68];
  float xp_s[16][8];
  float ab_s[2][64];
  float psum[4][128];
  float red_s[8][16][64];
  float sred[2][16][66];
};
struct PhiS {
  u16 h_s[32][72];
  u16 smu[32][264];
  u16 ssg[32][264];
  u16 sal[32][40];
  float xc_s[32][8];
  float clp_s[32][32];
  float alo_s[32][34];
  float bias_s[1088];
  float ab2[2][64];
};
union SmemU { ChainS c; PhiS p; };

// ====== fused: 128 producer blocks (chain) + 128 consumer blocks (phi), 512 thr each ======
__global__ __launch_bounds__(512) void fused_kernel(
    u16* __restrict__ newa, float* stats, int* flags, float* part,
    const float* __restrict__ X,
    const float* __restrict__ enc_w, const float* __restrict__ enc_b,
    const float* __restrict__ bn_g, const float* __restrict__ bn_b,
    const u16* __restrict__ At, const float* __restrict__ init_w,
    const u16* __restrict__ muWb, const u16* __restrict__ sigWb, const u16* __restrict__ alWb,
    const u16* __restrict__ muW2b, const u16* __restrict__ sigW2b, const u16* __restrict__ alW2b,
    const float* __restrict__ mub, const float* __restrict__ sigb, const float* __restrict__ alb,
    const float* __restrict__ mub2, const float* __restrict__ sigb2, const float* __restrict__ alb2,
    float* __restrict__ outp)
{
  __shared__ SmemU smem;
  const int tid = threadIdx.x;
  const int bid = blockIdx.x;
  const int lane = tid & 63, w = tid >> 6;
  const int m = lane & 15, q = lane >> 4;
  int* sflag = flags + 128;

  if (bid < 128) {
    // ==================== PRODUCER: sequential chain ====================
    const int n0 = bid * 16;
    for (int e = tid; e < 1024; e += 512) {
      int r = e >> 6, c0 = e & 63;
      smem.c.newf[r][c0] = bf2f(f2bf(init_w[c0]));
    }

    for (int t = 1; t < 128; ++t) {
      if (tid < 128) {
        int r = tid >> 3, k = tid & 7;
        smem.c.xp_s[r][k] = X[(size_t)(n0+r)*1024 + k*128 + (t-1)];
      }
      __syncthreads();                                  // (a)
      {
        int r = tid >> 5, d0 = (tid & 31) * 2;
        #pragma unroll
        for (int dd = 0; dd < 2; ++dd) {
          int d = d0 + dd;
          float a = enc_b[d];
          #pragma unroll
          for (int k = 0; k < 8; ++k) a = fmaf(smem.c.xp_s[r][k], enc_w[d*8+k], a);
          smem.c.enc_s[r][d] = a / (1.0f + fabsf(a));
        }
      }

      if (t >= 2) {
        if (w == 0) {
          for (;;) {
            int v0 = __hip_atomic_load(flags + lane*2,     AO, AS);
            int v1 = __hip_atomic_load(flags + lane*2 + 1, AO, AS);
            if (__ballot((v0 >= t-1) && (v1 >= t-1)) == ~0ull) break;
            __builtin_amdgcn_s_sleep(1);
          }
        }
        __syncthreads();                                // (a2)
        __atomic_signal_fence(__ATOMIC_ACQUIRE);
        {
          const int e = tid & 127, pr = tid >> 7;
          const float* pb = part + (size_t)((t-1)&1)*16384 + e;
          float s = 0.0f;
          #pragma unroll 16
          for (int p = pr*32; p < pr*32 + 32; ++p)
            s += __hip_atomic_load(pb + p*128, AO, AS);
          smem.c.psum[pr][e] = s;
        }
        __syncthreads();                                // (b1)
        if (bid == 0 && tid < 128) {                    // publish stats[t-1] (sc1, for consumers)
          float sv = smem.c.psum[0][tid] + smem.c.psum[1][tid] + smem.c.psum[2][tid] + smem.c.psum[3][tid];
          __hip_atomic_store(stats + (t-1)*128 + tid, sv, AO, AS);
        }
        if (tid < 64) {
          float S1 = smem.c.psum[0][tid] + smem.c.psum[1][tid] + smem.c.psum[2][tid] + smem.c.psum[3][tid];
          float S2 = smem.c.psum[0][tid+64] + smem.c.psum[1][tid+64] + smem.c.psum[2][tid+64] + smem.c.psum[3][tid+64];
          float mean = S1 * (1.0f/2048.0f);
          float var  = S2 * (1.0f/2048.0f) - mean*mean;
          float a = bn_g[tid] * rsqrtf(var + 1e-5f);
          smem.c.ab_s[0][tid] = a;
          smem.c.ab_s[1][tid] = fmaf(-a, mean, bn_b[tid]);
        }
      } else {
        if (tid < 64) {
          float mean = bf2f(f2bf(init_w[tid]));
          float a = bn_g[tid] * rsqrtf(1e-5f);
          smem.c.ab_s[0][tid] = a;
          smem.c.ab_s[1][tid] = fmaf(-a, mean, bn_b[tid]);
        }
      }
      __syncthreads();                                  // (b2) -- drains block0's stats stores
      if (bid == 0 && tid == 0 && t >= 2)
        __hip_atomic_store(sflag, t-1, AO, AS);

      #pragma unroll
      for (int e0 = 0; e0 < 1024; e0 += 512) {
        int e = e0 + tid;
        int mr = e >> 6, i = e & 63;
        smem.c.tmp_s[mr][i] = fmaf(smem.c.ab_s[0][i], smem.c.newf[mr][i], smem.c.ab_s[1][i]);
      }
      __syncthreads();                                  // (c)

      f32x4 acc[4];
      #pragma unroll
      for (int nt = 0; nt < 4; ++nt) acc[nt] = 0;

      #pragma unroll 4
      for (int it = 0; it < 16; ++it) {
        const int k0 = w*512 + it*32;
        const int i = k0 >> 6;
        const int dbase = (k0 & 63) + q*8;
        const float tv = smem.c.tmp_s[m][i];
        const f32x4 e0 = *reinterpret_cast<const f32x4*>(&smem.c.enc_s[m][dbase]);
        const f32x4 e1 = *reinterpret_cast<const f32x4*>(&smem.c.enc_s[m][dbase+4]);
        uint4v pk;
        pk[0] = pk2(tv*e0[0], tv*e0[1]);
        pk[1] = pk2(tv*e0[2], tv*e0[3]);
        pk[2] = pk2(tv*e1[0], tv*e1[1]);
        pk[3] = pk2(tv*e1[2], tv*e1[3]);
        short8 af = __builtin_bit_cast(short8, pk);
        const u16* bp = At + k0 + q*8;
        #pragma unroll
        for (int nt = 0; nt < 4; ++nt) {
          short8 bfv = *reinterpret_cast<const short8*>(bp + (nt*16 + m)*4096);
          acc[nt] = __builtin_amdgcn_mfma_f32_16x16x32_bf16(af, bfv, acc[nt], 0, 0, 0);
        }
      }
      #pragma unroll
      for (int nt = 0; nt < 4; ++nt)
        #pragma unroll
        for (int rg = 0; rg < 4; ++rg)
          smem.c.red_s[w][q*4+rg][nt*16+m] = acc[nt][rg];
      __syncthreads();                                  // (d)

      {
        u16* no = newa + (size_t)t*2048*64;
        const int r = tid >> 5;                 // 0..15
        const int c2 = (tid & 31) * 2;          // 0..62 even
        float v0 = 0.0f, v1 = 0.0f;
        #pragma unroll
        for (int p = 0; p < 8; ++p) { v0 += smem.c.red_s[p][r][c2]; v1 += smem.c.red_s[p][r][c2+1]; }
        smem.c.newf[r][c2]   = v0;
        smem.c.newf[r][c2+1] = v1;
        __hip_atomic_store((unsigned*)(no + (size_t)(n0+r)*64 + c2), pk2(v0, v1), AO, AS);
        smem.c.sred[0][r][c2]   = v0;  smem.c.sred[0][r][c2+1] = v1;
        smem.c.sred[1][r][c2]   = v0*v0; smem.c.sred[1][r][c2+1] = v1*v1;
      }
      __syncthreads();                                  // (e)
      if (tid < 64) {
        float S1 = 0.0f, S2 = 0.0f;
        #pragma unroll
        for (int r = 0; r < 16; ++r) { S1 += smem.c.sred[0][r][tid]; S2 += smem.c.sred[1][r][tid]; }
        float* pb = part + (size_t)(t&1)*16384 + bid*128;
        __hip_atomic_store(pb + tid,      S1, AO, AS);
        __hip_atomic_store(pb + 64 + tid, S2, AO, AS);
      }
      __syncthreads();                                  // (f) drains newa + part stores
      if (tid == 0)
        __hip_atomic_store(flags + bid, t, AO, AS);
    }

    // epilogue: block 0 publishes stats[127] + final sflag
    if (bid == 0) {
      if (w == 0) {
        for (;;) {
          int v0 = __hip_atomic_load(flags + lane*2,     AO, AS);
          int v1 = __hip_atomic_load(flags + lane*2 + 1, AO, AS);
          if (__ballot((v0 >= 127) && (v1 >= 127)) == ~0ull) break;
          __builtin_amdgcn_s_sleep(1);
        }
      }
      __syncthreads();
      __atomic_signal_fence(__ATOMIC_ACQUIRE);
      {
        const int e = tid & 127, pr = tid >> 7;
        const float* pb = part + (size_t)(127&1)*16384 + e;
        float s = 0.0f;
        #pragma unroll 16
        for (int p = pr*32; p < pr*32 + 32; ++p)
          s += __hip_atomic_load(pb + p*128, AO, AS);
        smem.c.psum[pr][e] = s;
      }
      __syncthreads();
      if (tid < 128) {
        float sv = smem.c.psum[0][tid] + smem.c.psum[1][tid] + smem.c.psum[2][tid] + smem.c.psum[3][tid];
        __hip_atomic_store(stats + 127*128 + tid, sv, AO, AS);
      }
      __syncthreads();
      if (tid == 0) __hip_atomic_store(sflag, 127, AO, AS);
    }

  } else {
    // ==================== CONSUMER: phi for 32 rows, one t-parity ====================
    const int cc  = bid - 128;
    const int n0p = (cc & 63) * 32;
    const int par = cc >> 6;
    const int r32 = tid >> 4;       // 0..31
    const int x16 = tid & 15;       // 0..15

    for (int e = tid; e < 1088; e += 512) {
      float v;
      if      (e < 256)  v = mub[e];
      else if (e < 512)  v = sigb[e-256];
      else if (e < 544)  v = alb[e-512];
      else if (e < 800)  v = mub2[e-544];
      else if (e < 1056) v = sigb2[e-800];
      else               v = alb2[e-1056];
      smem.p.bias_s[e] = v;
    }
    float nrm_acc = 0.0f;

    for (int kk = 0; kk < 64; ++kk) {
      const int t = 2*kk + par;
      if (t > 0 && tid == 0) {
        while (__hip_atomic_load(sflag, AO, AS) < t)
          __builtin_amdgcn_s_sleep(1);
      }
      __syncthreads();
      __atomic_signal_fence(__ATOMIC_ACQUIRE);
      if (tid < 64) {
        float s1 = __hip_atomic_load(stats + t*128 + tid,      AO, AS);
        float s2 = __hip_atomic_load(stats + t*128 + 64 + tid, AO, AS);
        float mean = s1 * (1.0f/2048.0f);
        float var  = s2 * (1.0f/2048.0f) - mean*mean;
        float a = bn_g[tid] * rsqrtf(var + 1e-5f);
        smem.p.ab2[0][tid] = a;
        smem.p.ab2[1][tid] = fmaf(-a, mean, bn_b[tid]);
      }
      __syncthreads();

      // P1: BN + softmax(h) + norm + xc (16 lanes/row, 4 cols each)
      {
        const u16* na = newa + (size_t)t*2048*64 + (size_t)(n0p + r32)*64 + x16*4;
        unsigned d0 = __hip_atomic_load((const unsigned*)na,     AO, AS);
        unsigned d1 = __hip_atomic_load((const unsigned*)na + 1, AO, AS);
        const int ib = x16*4;
        float tv[4];
        tv[0] = fmaf(smem.p.ab2[0][ib],   bf2f((u16)(d0 & 0xffff)), smem.p.ab2[1][ib]);
        tv[1] = fmaf(smem.p.ab2[0][ib+1], bf2f((u16)(d0 >> 16)),    smem.p.ab2[1][ib+1]);
        tv[2] = fmaf(smem.p.ab2[0][ib+2], bf2f((u16)(d1 & 0xffff)), smem.p.ab2[1][ib+2]);
        tv[3] = fmaf(smem.p.ab2[0][ib+3], bf2f((u16)(d1 >> 16)),    smem.p.ab2[1][ib+3]);
        float nacc = 0.0f, mx = -3.4e38f;
        #pragma unroll
        for (int j = 0; j < 4; ++j) { nacc = fmaf(tv[j], tv[j], nacc); mx = fmaxf(mx, tv[j]); }
        mx = fmaxf(mx, __shfl_xor(mx, 1));
        mx = fmaxf(mx, __shfl_xor(mx, 2));
        mx = fmaxf(mx, __shfl_xor(mx, 4));
        mx = fmaxf(mx, __shfl_xor(mx, 8));
        float se = 0.0f;
        #pragma unroll
        for (int j = 0; j < 4; ++j) { tv[j] = __expf(tv[j] - mx); se += tv[j]; }
        se += __shfl_xor(se, 1);
        se += __shfl_xor(se, 2);
        se += __shfl_xor(se, 4);
        se += __shfl_xor(se, 8);
        float inv = 1.0f / se;
        #pragma unroll
        for (int j = 0; j < 4; ++j) smem.p.h_s[r32][ib + j] = f2bf(tv[j] * inv);
        nacc += __shfl_xor(nacc, 1);
        nacc += __shfl_xor(nacc, 2);
        nacc += __shfl_xor(nacc, 4);
        nacc += __shfl_xor(nacc, 8);
        nacc += __shfl_xor(nacc, 16);
        nacc += __shfl_xor(nacc, 32);
        nrm_acc += nacc;                    // wave-total; flushed by lane 0 at end
        if (x16 < 8) smem.p.xc_s[r32][x16] = X[(size_t)(n0p+r32)*1024 + x16*128 + t];
      }
      __syncthreads();

      // P2: waves 0-3 -> mu (64 cols each); waves 4-7 -> sig; wave0 also alpha-L1
      {
        const u16* W1 = (w < 4) ? muWb : sigWb;
        const int boff = (w < 4) ? 0 : 256;
        const int coloff = (w & 3) * 64;
        f32x4 acc2[2][4];
        #pragma unroll
        for (int a_ = 0; a_ < 2; ++a_)
          #pragma unroll
          for (int b_ = 0; b_ < 4; ++b_) acc2[a_][b_] = 0;
        #pragma unroll
        for (int mt = 0; mt < 2; ++mt)
          #pragma unroll
          for (int kit = 0; kit < 2; ++kit) {
            short8 af = *reinterpret_cast<const short8*>(&smem.p.h_s[mt*16+m][kit*32 + q*8]);
            #pragma unroll
            for (int nt = 0; nt < 4; ++nt) {
              int c_ = coloff + nt*16 + m;
              short8 bfv = *reinterpret_cast<const short8*>(W1 + c_*64 + kit*32 + q*8);
              acc2[mt][nt] = __builtin_amdgcn_mfma_f32_16x16x32_bf16(af, bfv, acc2[mt][nt], 0, 0, 0);
            }
          }
        #pragma unroll
        for (int mt = 0; mt < 2; ++mt)
          #pragma unroll
          for (int nt = 0; nt < 4; ++nt) {
            int col = coloff + nt*16 + m;
            float bia = smem.p.bias_s[boff + col];
            #pragma unroll
            for (int rg = 0; rg < 4; ++rg) {
              int row = mt*16 + q*4 + rg;
              float v = acc2[mt][nt][rg] + bia;
              v = v / (1.0f + fabsf(v));
              ((w < 4) ? smem.p.smu : smem.p.ssg)[row][col] = f2bf(v);
            }
          }
      }
      if (w == 0) {  // alpha layer-1
        f32x4 aacc[2][2];
        aacc[0][0] = 0; aacc[0][1] = 0; aacc[1][0] = 0; aacc[1][1] = 0;
        #pragma unroll
        for (int mt = 0; mt < 2; ++mt)
          #pragma unroll
          for (int kit = 0; kit < 2; ++kit) {
            short8 af = *reinterpret_cast<const short8*>(&smem.p.h_s[mt*16+m][kit*32 + q*8]);
            #pragma unroll
            for (int nt = 0; nt < 2; ++nt) {
              short8 bfv = *reinterpret_cast<const short8*>(alWb + (nt*16+m)*64 + kit*32 + q*8);
              aacc[mt][nt] = __builtin_amdgcn_mfma_f32_16x16x32_bf16(af, bfv, aacc[mt][nt], 0, 0, 0);
            }
          }
        #pragma unroll
        for (int mt = 0; mt < 2; ++mt)
          #pragma unroll
          for (int nt = 0; nt < 2; ++nt) {
            int col = nt*16 + m;
            float bia = smem.p.bias_s[512 + col];
            #pragma unroll
            for (int rg = 0; rg < 4; ++rg) {
              int row = mt*16 + q*4 + rg;
              float v = aacc[mt][nt][rg] + bia;
              v = v / (1.0f + fabsf(v));
              smem.p.sal[row][col] = f2bf(v);
            }
          }
      }
      __syncthreads();

      // P3: wave w -> cols [32w, 32w+32) of layer-2 mu+sig, fused GMM comp_lp; wave0: al2
      {
        #pragma unroll 1
        for (int mt = 0; mt < 2; ++mt) {
          f32x4 accm[2], accs[2];
          accm[0] = 0; accm[1] = 0; accs[0] = 0; accs[1] = 0;
          for (int kit = 0; kit < 8; ++kit) {
            short8 am_ = *reinterpret_cast<const short8*>(&smem.p.smu[mt*16+m][kit*32 + q*8]);
            short8 as_ = *reinterpret_cast<const short8*>(&smem.p.ssg[mt*16+m][kit*32 + q*8]);
            #pragma unroll
            for (int nt = 0; nt < 2; ++nt) {
              int cb = w*32 + nt*16 + m;
              short8 bm = *reinterpret_cast<const short8*>(muW2b + cb*256 + kit*32 + q*8);
              short8 bs = *reinterpret_cast<const short8*>(sigW2b + cb*256 + kit*32 + q*8);
              accm[nt] = __builtin_amdgcn_mfma_f32_16x16x32_bf16(am_, bm, accm[nt], 0, 0, 0);
              accs[nt] = __builtin_amdgcn_mfma_f32_16x16x32_bf16(as_, bs, accs[nt], 0, 0, 0);
            }
          }
          #pragma unroll
          for (int nt = 0; nt < 2; ++nt) {
            int col = w*32 + nt*16 + m;
            int cmix = col >> 3, x = col & 7;
            float bmu = smem.p.bias_s[544 + col], bsg = smem.p.bias_s[800 + col];
            #pragma unroll
            for (int rg = 0; rg < 4; ++rg) {
              int row = mt*16 + q*4 + rg;
              float muv = accm[nt][rg] + bmu;
              float lsv = accs[nt][rg] + bsg;
              float z = (smem.p.xc_s[row][x] - muv) * __expf(-lsv);
              float tt = fmaf(-0.5f*z, z, -lsv) - LOG2PI_HALF;
              tt += __shfl_xor(tt, 1);
              tt += __shfl_xor(tt, 2);
              tt += __shfl_xor(tt, 4);
              if (x == 0) smem.p.clp_s[row][cmix] = tt;
            }
          }
        }
        if (w == 0) {  // alpha layer-2
          #pragma unroll
          for (int mt = 0; mt < 2; ++mt) {
            f32x4 aacc[2]; aacc[0] = 0; aacc[1] = 0;
            short8 aa = *reinterpret_cast<const short8*>(&smem.p.sal[mt*16+m][q*8]);
            #pragma unroll
            for (int nt = 0; nt < 2; ++nt) {
              short8 bb = *reinterpret_cast<const short8*>(alW2b + (nt*16+m)*32 + q*8);
              aacc[nt] = __builtin_amdgcn_mfma_f32_16x16x32_bf16(aa, bb, aacc[nt], 0, 0, 0);
            }
            #pragma unroll
            for (int nt = 0; nt < 2; ++nt) {
              int col = nt*16 + m;
              float bia = smem.p.bias_s[1056 + col];
              #pragma unroll
              for (int rg = 0; rg < 4; ++rg)
                smem.p.alo_s[mt*16 + q*4 + rg][col] = aacc[nt][rg] + bia;
            }
          }
        }
      }
      __syncthreads();

      // P5: log_softmax(alpha) + comp_lp -> logsumexp -> res  (16 lanes/row, 2 comps each)
      {
        const int r = r32, jj = x16;
        float av[2], am = -3.4e38f;
        #pragma unroll
        for (int u = 0; u < 2; ++u) { av[u] = smem.p.alo_s[r][jj + u*16]; am = fmaxf(am, av[u]); }
        am = fmaxf(am, __shfl_xor(am, 1));
        am = fmaxf(am, __shfl_xor(am, 2));
        am = fmaxf(am, __shfl_xor(am, 4));
        am = fmaxf(am, __shfl_xor(am, 8));
        float se = 0.0f;
        #pragma unroll
        for (int u = 0; u < 2; ++u) se += __expf(av[u] - am);
        se += __shfl_xor(se, 1);
        se += __shfl_xor(se, 2);
        se += __shfl_xor(se, 4);
        se += __shfl_xor(se, 8);
        float la = am + __logf(se);
        float tt2[2], tm = -3.4e38f;
        #pragma unroll
        for (int u = 0; u < 2; ++u) {
          tt2[u] = av[u] - la + smem.p.clp_s[r][jj + u*16];
          tm = fmaxf(tm, tt2[u]);
        }
        tm = fmaxf(tm, __shfl_xor(tm, 1));
        tm = fmaxf(tm, __shfl_xor(tm, 2));
        tm = fmaxf(tm, __shfl_xor(tm, 4));
        tm = fmaxf(tm, __shfl_xor(tm, 8));
        float ts = 0.0f;
        #pragma unroll
        for (int u = 0; u < 2; ++u) ts += __expf(tt2[u] - tm);
        ts += __shfl_xor(ts, 1);
        ts += __shfl_xor(ts, 2);
        ts += __shfl_xor(ts, 4);
        ts += __shfl_xor(ts, 8);
        if (jj == 0) atomicAdd(&outp[n0p + r], tm + __logf(ts));
      }
      __syncthreads();
    }
    if (lane == 0) atomicAdd(&outp[2048], nrm_acc);
  }
}

extern "C" void kernel_launch(void* const* d_in, const int* in_sizes, int n_in,
                              void* d_out, int out_size, void* d_ws, size_t ws_size,
                              hipStream_t stream) {
  const float* X      = (const float*)d_in[0];
  const float* enc_w  = (const float*)d_in[1];
  const float* enc_b  = (const float*)d_in[2];
  const float* init_w = (const float*)d_in[3];
  const float* A      = (const float*)d_in[4];
  const float* bn_g   = (const float*)d_in[5];
  const float* bn_b   = (const float*)d_in[6];
  const float* muW    = (const float*)d_in[7];
  const float* mub    = (const float*)d_in[8];
  const float* muW2   = (const float*)d_in[9];
  const float* mub2   = (const float*)d_in[10];
  const float* sigW   = (const float*)d_in[11];
  const float* sigb   = (const float*)d_in[12];
  const float* sigW2  = (const float*)d_in[13];
  const float* sigb2  = (const float*)d_in[14];
  const float* alW    = (const float*)d_in[15];
  const float* alb    = (const float*)d_in[16];
  const float* alW2   = (const float*)d_in[17];
  const float* alb2   = (const float*)d_in[18];

  if (ws_size < WS_NEED) return;

  char* ws = (char*)d_ws;
  float* stats = (float*)(ws + OFF_STATS);
  u16* newa    = (u16*)(ws + OFF_NEW);
  u16* At      = (u16*)(ws + OFF_AT);
  u16* muWb    = (u16*)(ws + OFF_MUW);
  u16* sigWb   = (u16*)(ws + OFF_SIGW);
  u16* alWb    = (u16*)(ws + OFF_ALW);
  u16* muW2b   = (u16*)(ws + OFF_MUW2);
  u16* sigW2b  = (u16*)(ws + OFF_SIGW2);
  u16* alW2b   = (u16*)(ws + OFF_ALW2);
  int* flags   = (int*)(ws + OFF_CNT);
  float* part  = (float*)(ws + OFF_PART);

  (void)hipMemsetAsync(d_out, 0, (size_t)out_size * sizeof(float), stream);
  (void)hipMemsetAsync(stats, 0, (size_t)128 * 128 * sizeof(float), stream);
  (void)hipMemsetAsync(flags, 0, 1024, stream);

  init_kernel<<<dim3(1024), dim3(256), 0, stream>>>(
      A, init_w, muW, sigW, alW, muW2, sigW2, alW2,
      At, newa, stats, muWb, sigWb, alWb, muW2b, sigW2b, alW2b);

  {
    u16* newa_a = newa; float* stats_a = stats; int* flags_a = flags; float* part_a = part;
    const float *X_a = X, *encw_a = enc_w, *encb_a = enc_b, *bng_a = bn_g, *bnb_a = bn_b, *initw_a = init_w;
    const u16 *At_a = At, *muWb_a = muWb, *sigWb_a = sigWb, *alWb_a = alWb,
              *muW2b_a = muW2b, *sigW2b_a = sigW2b, *alW2b_a = alW2b;
    const float *mub_a = mub, *sigb_a = sigb, *alb_a = alb, *mub2_a = mub2, *sigb2_a = sigb2, *alb2_a = alb2;
    float* outp_a = (float*)d_out;
    void* args[] = { (void*)&newa_a, (void*)&stats_a, (void*)&flags_a, (void*)&part_a, (void*)&X_a,
                     (void*)&encw_a, (void*)&encb_a, (void*)&bng_a, (void*)&bnb_a, (void*)&At_a, (void*)&initw_a,
                     (void*)&muWb_a, (void*)&sigWb_a, (void*)&alWb_a,
                     (void*)&muW2b_a, (void*)&sigW2b_a, (void*)&alW2b_a,
                     (void*)&mub_a, (void*)&sigb_a, (void*)&alb_a,
                     (void*)&mub2_a, (void*)&sigb2_a, (void*)&alb2_a,
                     (void*)&outp_a };
    (void)hipLaunchCooperativeKernel((void*)fused_kernel, dim3(256), dim3(512), args, 0, stream);
  }
}